// Round 6
// baseline (695.432 us; speedup 1.0000x reference)
//
#include <hip/hip_runtime.h>

#define HIDDEN 128
#define NRBF 50
#define CUTOFF_F 5.0f
#define PI_OVER_CUTOFF 0.6283185307179586f
#define TPB_TILES 8   // tiles (of 64 edges) per block

typedef __attribute__((ext_vector_type(2))) _Float16 hf2;
typedef _Float16 half8_t __attribute__((ext_vector_type(8)));
using f32x4_t  = __attribute__((ext_vector_type(4))) float;
using short8_t = __attribute__((ext_vector_type(8))) short;

static __device__ __forceinline__ unsigned int pkh(float a, float b) {
    return __builtin_bit_cast(unsigned int, __builtin_amdgcn_cvt_pkrtz(a, b));
}

// fp32 pair -> packed bf16x2 (RNE) for the combine GEMM
static __device__ __forceinline__ unsigned int pk_bf16(float a, float b) {
    unsigned int ua = __float_as_uint(a), ub = __float_as_uint(b);
    ua = (ua + 0x7FFFu + ((ua >> 16) & 1u)) >> 16;
    ub = (ub + 0x7FFFu + ((ub >> 16) & 1u)) >> 16;
    return ua | (ub << 16);
}

// ======================= CSR build =======================

__global__ __launch_bounds__(256) void hist_kernel(
    const int* __restrict__ ei, const float* __restrict__ ew,
    int* __restrict__ cnt, int E)
{
    int e = blockIdx.x * 256 + threadIdx.x;
    if (e >= E) return;
    float r = ew[e];
    if (r < CUTOFF_F) atomicAdd(&cnt[ei[e]], 1);
}

__global__ __launch_bounds__(256) void scan1_kernel(
    const int* __restrict__ cnt, int* __restrict__ rowptr,
    int* __restrict__ bsum, int N)
{
    __shared__ int sh[256];
    int t = threadIdx.x, b = blockIdx.x;
    int base = b * 1024 + t * 4;
    int v[4];
#pragma unroll
    for (int j = 0; j < 4; ++j) v[j] = (base + j < N) ? cnt[base + j] : 0;
    int s = v[0] + v[1] + v[2] + v[3];
    sh[t] = s;
    __syncthreads();
    for (int off = 1; off < 256; off <<= 1) {
        int x = (t >= off) ? sh[t - off] : 0;
        __syncthreads();
        sh[t] += x;
        __syncthreads();
    }
    int run = sh[t] - s;
#pragma unroll
    for (int j = 0; j < 4; ++j) {
        if (base + j < N) rowptr[base + j] = run;
        run += v[j];
    }
    if (t == 255) bsum[b] = sh[255];
}

__global__ __launch_bounds__(256) void scan2_kernel(
    int* __restrict__ bsum, int* __restrict__ rowptr, int nb, int N)
{
    __shared__ int sh[256];
    int t = threadIdx.x;
    int v = (t < nb) ? bsum[t] : 0;
    sh[t] = v;
    __syncthreads();
    for (int off = 1; off < 256; off <<= 1) {
        int x = (t >= off) ? sh[t - off] : 0;
        __syncthreads();
        sh[t] += x;
        __syncthreads();
    }
    if (t < nb) bsum[t] = sh[t] - v;
    if (t == 255) rowptr[N] = sh[255];
}

__global__ __launch_bounds__(256) void scan3_kernel(
    int* __restrict__ rowptr, int* __restrict__ woff,
    const int* __restrict__ bsum, int N)
{
    int t = threadIdx.x, b = blockIdx.x;
    int base = b * 1024 + t * 4;
    int off = bsum[b];
#pragma unroll
    for (int j = 0; j < 4; ++j) {
        int i = base + j;
        if (i < N) {
            int r = rowptr[i] + off;
            rowptr[i] = r;
            woff[i] = r;
        }
    }
}

// scatter live edges into CSR slots: int4{src|zt<<20, eid, C_bits, 0}
__global__ __launch_bounds__(256) void scatter_kernel(
    const int* __restrict__ z, const int* __restrict__ ei,
    const float* __restrict__ ew, int* __restrict__ woff,
    int4* __restrict__ slots, int E)
{
    int e = blockIdx.x * 256 + threadIdx.x;
    if (e >= E) return;
    float r = ew[e];
    if (!(r < CUTOFF_F)) return;
    float C = 0.5f * (cosf(r * PI_OVER_CUTOFF) + 1.0f);
    int src = ei[e];
    int dst = ei[E + e];
    int zt  = z[dst];
    int p = atomicAdd(&woff[src], 1);
    slots[p] = make_int4(src | (zt << 20), e, __float_as_int(C), 0);
}

// ======================= MFMA edge gather =======================
// W = [C*ea | C | 0pad](Mx64) @ [dpw | dpb | 0](64x128) via 16x16x32 f16 MFMA.
// Block = 4 waves, TPB_TILES tiles of 64 edges. B staged once per block in
// LDS (pitch 36 u32). Epilogue: lane holds 4 edges x 8 h; multiply by emb
// (L2-resident), merge equal-src runs in registers, flush with atomics.
__global__ __launch_bounds__(256) void gather_mfma(
    const int* __restrict__ rowptr, const int4* __restrict__ slots,
    const float* __restrict__ ea, const float* __restrict__ emb,
    const float* __restrict__ dpw, const float* __restrict__ dpb,
    float* __restrict__ agg, int N)
{
    __shared__ unsigned int B_lds[128 * 36];
    __shared__ int   s_src[TPB_TILES * 64];
    __shared__ int   s_eid[TPB_TILES * 64];
    __shared__ int   s_zt [TPB_TILES * 64];
    __shared__ float s_C  [TPB_TILES * 64];

    int M = rowptr[N];                      // live edge count

    // bijective XCD-chunk swizzle (consecutive logical blocks -> same XCD)
    int nwg = gridDim.x, orig = blockIdx.x;
    int q = nwg >> 3, r8 = nwg & 7, xcd = orig & 7, sub = orig >> 3;
    int lb = (xcd < r8) ? xcd * (q + 1) + sub
                        : r8 * (q + 1) + (xcd - r8) * q + sub;
    int gbase = lb * (TPB_TILES * 64);
    if (gbase >= M) return;

    int tid  = threadIdx.x;
    int w    = tid >> 6;
    int lane = tid & 63;
    int c    = lane & 15;
    int g    = lane >> 4;

    // stage B (dpw ext) as f16 pairs: B_lds[h][p], p = k-pair 0..31
    for (int idx = tid; idx < 128 * 32; idx += 256) {
        int h = idx >> 5, p = idx & 31;
        unsigned int u = 0u;
        if (p < 25) {
            float2 v = *(const float2*)(dpw + h * NRBF + 2 * p);
            u = pkh(v.x, v.y);
        } else if (p == 25) {
            u = pkh(dpb[h], 0.f);
        }
        B_lds[h * 36 + p] = u;
    }
    // stage descriptors for all tiles of this block
    for (int i = tid; i < TPB_TILES * 64; i += 256) {
        int gi = gbase + i;
        if (gi < M) {
            int4 sl = slots[gi];
            s_src[i] = sl.x & 0xFFFFF;
            s_zt[i]  = (unsigned int)sl.x >> 20;
            s_eid[i] = sl.y;
            s_C[i]   = __int_as_float(sl.z);
        } else {
            s_src[i] = 0; s_zt[i] = 0; s_eid[i] = 0; s_C[i] = 0.f;
        }
    }
    __syncthreads();

    // hoist B fragments to registers: [nt][kstep]
    half8_t bfrag[8][2];
#pragma unroll
    for (int nt = 0; nt < 8; ++nt)
#pragma unroll
        for (int ks = 0; ks < 2; ++ks) {
            uint4 bu = *(const uint4*)&B_lds[(nt * 16 + c) * 36 + ks * 16 + g * 4];
            bfrag[nt][ks] = __builtin_bit_cast(half8_t, bu);
        }

    for (int t = 0; t < TPB_TILES; ++t) {
        if (gbase + t * 64 >= M) break;
        // ---- A fragments (16 edges per wave) ----
        int eloc = t * 64 + w * 16 + c;
        int   eid = s_eid[eloc];
        float Cv  = s_C[eloc];
        const float* row = ea + (size_t)eid * NRBF;
        uint4 a0u, a1u;
        {
            float4 q0 = *(const float4*)(row + g * 8);
            float4 q1 = *(const float4*)(row + g * 8 + 4);
            a0u = make_uint4(pkh(Cv * q0.x, Cv * q0.y), pkh(Cv * q0.z, Cv * q0.w),
                             pkh(Cv * q1.x, Cv * q1.y), pkh(Cv * q1.z, Cv * q1.w));
        }
        if (g < 2) {
            float4 q0 = *(const float4*)(row + 32 + g * 8);
            float4 q1 = *(const float4*)(row + 36 + g * 8);
            a1u = make_uint4(pkh(Cv * q0.x, Cv * q0.y), pkh(Cv * q0.z, Cv * q0.w),
                             pkh(Cv * q1.x, Cv * q1.y), pkh(Cv * q1.z, Cv * q1.w));
        } else if (g == 2) {
            float2 tv = *(const float2*)(row + 48);
            a1u = make_uint4(pkh(Cv * tv.x, Cv * tv.y), pkh(Cv, 0.f), 0u, 0u);
        } else {
            a1u = make_uint4(0u, 0u, 0u, 0u);
        }
        half8_t A0 = __builtin_bit_cast(half8_t, a0u);
        half8_t A1 = __builtin_bit_cast(half8_t, a1u);

        // ---- MFMA: W tile (16 edges x 128 h per wave) ----
        f32x4_t acc[8];
#pragma unroll
        for (int nt = 0; nt < 8; ++nt) acc[nt] = (f32x4_t){0.f, 0.f, 0.f, 0.f};
#pragma unroll
        for (int nt = 0; nt < 8; ++nt) {
            acc[nt] = __builtin_amdgcn_mfma_f32_16x16x32_f16(A0, bfrag[nt][0], acc[nt], 0, 0, 0);
            acc[nt] = __builtin_amdgcn_mfma_f32_16x16x32_f16(A1, bfrag[nt][1], acc[nt], 0, 0, 0);
        }

        // ---- epilogue: msg = W * emb[zt], run-merged atomic scatter ----
        int rbase = t * 64 + w * 16 + g * 4;
        int sprev = s_src[rbase];
        float racc[8];
        {
            const float* er = emb + (size_t)s_zt[rbase] * HIDDEN;
#pragma unroll
            for (int nt = 0; nt < 8; ++nt) racc[nt] = acc[nt][0] * er[nt * 16 + c];
        }
#pragma unroll
        for (int r = 1; r < 4; ++r) {
            int s = s_src[rbase + r];
            const float* er = emb + (size_t)s_zt[rbase + r] * HIDDEN;
            if (s != sprev) {
                float* dst = agg + (size_t)sprev * HIDDEN;
#pragma unroll
                for (int nt = 0; nt < 8; ++nt) {
                    unsafeAtomicAdd(dst + nt * 16 + c, racc[nt]);
                    racc[nt] = 0.f;
                }
                sprev = s;
            }
#pragma unroll
            for (int nt = 0; nt < 8; ++nt)
                racc[nt] = fmaf(acc[nt][r], er[nt * 16 + c], racc[nt]);
        }
        {
            float* dst = agg + (size_t)sprev * HIDDEN;
#pragma unroll
            for (int nt = 0; nt < 8; ++nt)
                unsafeAtomicAdd(dst + nt * 16 + c, racc[nt]);
        }
    }
}

// ======================= Fallback edge kernel (atomics) =======================
__global__ __launch_bounds__(256) void edge_kernel(
    const int* __restrict__ z, const int* __restrict__ ei,
    const float* __restrict__ ew, const float* __restrict__ ea,
    const float* __restrict__ emb, const float* __restrict__ dpw,
    const float* __restrict__ dpb, float* __restrict__ agg, int E)
{
    int e = blockIdx.x * 256 + threadIdx.x;
    if (e >= E) return;
    float r = ew[e];
    if (!(r < CUTOFF_F)) return;
    float C = 0.5f * (cosf(r * PI_OVER_CUTOFF) + 1.0f);
    int src = ei[e];
    int dst = ei[E + e];
    int zt  = z[dst];
    float av[NRBF];
#pragma unroll
    for (int k = 0; k < NRBF; ++k) av[k] = ea[(size_t)e * NRBF + k];
    const float* er = emb + (size_t)zt * HIDDEN;
    float*       ar = agg + (size_t)src * HIDDEN;
#pragma unroll 2
    for (int h = 0; h < HIDDEN; ++h) {
        const float* wrow = dpw + h * NRBF;
        float s0 = 0.f, s1 = 0.f;
#pragma unroll
        for (int k = 0; k < NRBF; k += 2) {
            s0 = fmaf(av[k],     wrow[k],     s0);
            s1 = fmaf(av[k + 1], wrow[k + 1], s1);
        }
        float w = (dpb[h] + s0 + s1) * C;
        unsafeAtomicAdd(&ar[h], w * er[h]);
    }
}

// ======================= Combine: bf16 MFMA GEMM =======================
__global__ __launch_bounds__(256) void combine_mfma(
    const float* __restrict__ nf, const float* __restrict__ cw,
    const float* __restrict__ cbias, float* out, int N)
{
    __shared__ unsigned int As_u[64 * 20];
    __shared__ unsigned int Bs_u[128 * 20];
    int tid  = threadIdx.x;
    int w    = tid >> 6;
    int lane = tid & 63;
    int c    = lane & 15;
    int g    = lane >> 4;
    int row0 = blockIdx.x * 64;

    f32x4_t acc[8];
#pragma unroll
    for (int q = 0; q < 8; ++q) acc[q] = (f32x4_t){0.f, 0.f, 0.f, 0.f};

    for (int ks = 0; ks < 8; ++ks) {
        const float* src = (ks < 4) ? nf : out;
        int kb = (ks & 3) * 32;
        {
            int r = tid >> 2, kq = tid & 3;
            int row = row0 + r;
            float4 v0 = make_float4(0.f, 0.f, 0.f, 0.f), v1 = v0;
            if (row < N) {
                const float4* p = (const float4*)(src + (size_t)row * HIDDEN + kb + kq * 8);
                v0 = p[0]; v1 = p[1];
            }
            *(uint4*)&As_u[r * 20 + kq * 4] =
                make_uint4(pk_bf16(v0.x, v0.y), pk_bf16(v0.z, v0.w),
                           pk_bf16(v1.x, v1.y), pk_bf16(v1.z, v1.w));
        }
        {
            int j = tid >> 1, hf = tid & 1;
            const float4* p = (const float4*)(cw + (size_t)j * 256 + ks * 32 + hf * 16);
            float4 b0 = p[0], b1 = p[1], b2 = p[2], b3 = p[3];
            *(uint4*)&Bs_u[j * 20 + hf * 8] =
                make_uint4(pk_bf16(b0.x, b0.y), pk_bf16(b0.z, b0.w),
                           pk_bf16(b1.x, b1.y), pk_bf16(b1.z, b1.w));
            *(uint4*)&Bs_u[j * 20 + hf * 8 + 4] =
                make_uint4(pk_bf16(b2.x, b2.y), pk_bf16(b2.z, b2.w),
                           pk_bf16(b3.x, b3.y), pk_bf16(b3.z, b3.w));
        }
        __syncthreads();
        uint4 au = *(const uint4*)&As_u[(w * 16 + c) * 20 + g * 4];
        short8_t af = __builtin_bit_cast(short8_t, au);
#pragma unroll
        for (int cbk = 0; cbk < 8; ++cbk) {
            uint4 bu = *(const uint4*)&Bs_u[(cbk * 16 + c) * 20 + g * 4];
            short8_t bf = __builtin_bit_cast(short8_t, bu);
            acc[cbk] = __builtin_amdgcn_mfma_f32_16x16x32_bf16(af, bf, acc[cbk], 0, 0, 0);
        }
        __syncthreads();
    }
#pragma unroll
    for (int cbk = 0; cbk < 8; ++cbk) {
        float bias = cbias[cbk * 16 + c];
#pragma unroll
        for (int r = 0; r < 4; ++r) {
            int row = row0 + w * 16 + g * 4 + r;
            if (row < N) out[(size_t)row * HIDDEN + cbk * 16 + c] = acc[cbk][r] + bias;
        }
    }
}

// ======================= launch =======================

extern "C" void kernel_launch(void* const* d_in, const int* in_sizes, int n_in,
                              void* d_out, int out_size, void* d_ws, size_t ws_size,
                              hipStream_t stream)
{
    const int*   z   = (const int*)  d_in[0];
    const float* nf  = (const float*)d_in[1];
    const int*   ei  = (const int*)  d_in[2];
    const float* ew  = (const float*)d_in[3];
    const float* ea  = (const float*)d_in[4];
    const float* emb = (const float*)d_in[5];
    const float* dpw = (const float*)d_in[6];
    const float* dpb = (const float*)d_in[7];
    const float* cw  = (const float*)d_in[8];
    const float* cb  = (const float*)d_in[9];
    float* out = (float*)d_out;

    int N = in_sizes[0];
    int E = in_sizes[3];

    size_t hdr = ((size_t)2 * N + 1 + 1024 + 3) & ~(size_t)3;   // u32s, 16B-align slots
    size_t need = hdr * 4 + (size_t)E * 16;

    // agg accumulator lives in d_out; atomics + empty rows need zeros
    (void)hipMemsetAsync(out, 0, (size_t)N * HIDDEN * sizeof(float), stream);

    if (ws_size >= need) {
        int*  rowptr = (int*)d_ws;                 // N+1
        int*  woff   = rowptr + (N + 1);           // N
        int*  bsum   = woff + N;                   // 1024
        int4* slots  = (int4*)((unsigned int*)d_ws + hdr);   // E slots

        int nb1 = (N + 1023) / 1024;

        (void)hipMemsetAsync(woff, 0, (size_t)N * 4, stream);
        hist_kernel<<<(E + 255) / 256, 256, 0, stream>>>(ei, ew, woff, E);
        scan1_kernel<<<nb1, 256, 0, stream>>>(woff, rowptr, bsum, N);
        scan2_kernel<<<1, 256, 0, stream>>>(bsum, rowptr, nb1, N);
        scan3_kernel<<<nb1, 256, 0, stream>>>(rowptr, woff, bsum, N);
        scatter_kernel<<<(E + 255) / 256, 256, 0, stream>>>(z, ei, ew, woff,
                                                            slots, E);
        int nblk = (E + TPB_TILES * 64 - 1) / (TPB_TILES * 64);
        gather_mfma<<<nblk, 256, 0, stream>>>(rowptr, slots, ea, emb,
                                              dpw, dpb, out, N);
    } else {
        edge_kernel<<<(E + 255) / 256, 256, 0, stream>>>(z, ei, ew, ea, emb,
                                                         dpw, dpb, out, E);
    }

    combine_mfma<<<(N + 63) / 64, 256, 0, stream>>>(nf, cw, cb, out, N);
}

// Round 7
// 564.183 us; speedup vs baseline: 1.2326x; 1.2326x over previous
//
#include <hip/hip_runtime.h>

#define HIDDEN 128
#define NRBF 50
#define CUTOFF_F 5.0f
#define PI_OVER_CUTOFF 0.6283185307179586f
#define SLOT_U32 28      // 112B packed A-row per live edge
#define EPB 512          // edges per block in gather (4 waves x 128)

typedef _Float16 half8_t __attribute__((ext_vector_type(8)));
using f32x4_t  = __attribute__((ext_vector_type(4))) float;
using short8_t = __attribute__((ext_vector_type(8))) short;
typedef __attribute__((ext_vector_type(2))) _Float16 hf2;

static __device__ __forceinline__ unsigned int pkh(float a, float b) {
    return __builtin_bit_cast(unsigned int, __builtin_amdgcn_cvt_pkrtz(a, b));
}
static __device__ __forceinline__ unsigned int pk_bf16(float a, float b) {
    unsigned int ua = __float_as_uint(a), ub = __float_as_uint(b);
    ua = (ua + 0x7FFFu + ((ua >> 16) & 1u)) >> 16;
    ub = (ub + 0x7FFFu + ((ub >> 16) & 1u)) >> 16;
    return ua | (ub << 16);
}

// ======================= CSR build =======================

__global__ __launch_bounds__(256) void hist_kernel(
    const int* __restrict__ ei, const float* __restrict__ ew,
    int* __restrict__ cnt, int E)
{
    int e = blockIdx.x * 256 + threadIdx.x;
    if (e >= E) return;
    float r = ew[e];
    if (r < CUTOFF_F) atomicAdd(&cnt[ei[e]], 1);
}

__global__ __launch_bounds__(256) void scan1_kernel(
    const int* __restrict__ cnt, int* __restrict__ rowptr,
    int* __restrict__ bsum, int N)
{
    __shared__ int sh[256];
    int t = threadIdx.x, b = blockIdx.x;
    int base = b * 1024 + t * 4;
    int v[4];
#pragma unroll
    for (int j = 0; j < 4; ++j) v[j] = (base + j < N) ? cnt[base + j] : 0;
    int s = v[0] + v[1] + v[2] + v[3];
    sh[t] = s;
    __syncthreads();
    for (int off = 1; off < 256; off <<= 1) {
        int x = (t >= off) ? sh[t - off] : 0;
        __syncthreads();
        sh[t] += x;
        __syncthreads();
    }
    int run = sh[t] - s;
#pragma unroll
    for (int j = 0; j < 4; ++j) {
        if (base + j < N) rowptr[base + j] = run;
        run += v[j];
    }
    if (t == 255) bsum[b] = sh[255];
}

__global__ __launch_bounds__(256) void scan2_kernel(
    int* __restrict__ bsum, int* __restrict__ rowptr, int nb, int N)
{
    __shared__ int sh[256];
    int t = threadIdx.x;
    int v = (t < nb) ? bsum[t] : 0;
    sh[t] = v;
    __syncthreads();
    for (int off = 1; off < 256; off <<= 1) {
        int x = (t >= off) ? sh[t - off] : 0;
        __syncthreads();
        sh[t] += x;
        __syncthreads();
    }
    if (t < nb) bsum[t] = sh[t] - v;
    if (t == 255) rowptr[N] = sh[255];
}

__global__ __launch_bounds__(256) void scan3_kernel(
    int* __restrict__ rowptr, int* __restrict__ woff,
    const int* __restrict__ bsum, int N)
{
    int t = threadIdx.x, b = blockIdx.x;
    int base = b * 1024 + t * 4;
    int off = bsum[b];
#pragma unroll
    for (int j = 0; j < 4; ++j) {
        int i = base + j;
        if (i < N) {
            int r = rowptr[i] + off;
            rowptr[i] = r;
            woff[i] = r;
        }
    }
}

// tier-1 scatter: CSR-reorder + pre-pack A-row (C*ea | C | 0) as f16, 112B
__global__ __launch_bounds__(256) void scatter_pack(
    const int* __restrict__ z, const int* __restrict__ ei,
    const float* __restrict__ ew, const float* __restrict__ ea,
    int* __restrict__ woff, int* __restrict__ desc,
    unsigned int* __restrict__ slots, int E)
{
    int e = blockIdx.x * 256 + threadIdx.x;
    if (e >= E) return;
    float r = ew[e];
    if (!(r < CUTOFF_F)) return;
    float C = 0.5f * (cosf(r * PI_OVER_CUTOFF) + 1.0f);
    int src = ei[e];
    int dst = ei[E + e];
    int zt  = z[dst];
    int p = atomicAdd(&woff[src], 1);
    desc[p] = src | (zt << 20);

    unsigned int buf[SLOT_U32];
    const float2* rp = (const float2*)(ea + (size_t)e * NRBF);
#pragma unroll
    for (int q = 0; q < 25; ++q) {
        float2 v = rp[q];
        buf[q] = pkh(C * v.x, C * v.y);
    }
    buf[25] = pkh(C, 0.f);
    buf[26] = 0u; buf[27] = 0u;
    uint4* sp = (uint4*)(slots + (size_t)p * SLOT_U32);
#pragma unroll
    for (int q = 0; q < 7; ++q) sp[q] = ((const uint4*)buf)[q];
}

// tier-2 scatter: descriptors only
__global__ __launch_bounds__(256) void scatter_simple(
    const int* __restrict__ z, const int* __restrict__ ei,
    const float* __restrict__ ew, int* __restrict__ woff,
    int* __restrict__ desc, float* __restrict__ cCA, int* __restrict__ eidA,
    int E)
{
    int e = blockIdx.x * 256 + threadIdx.x;
    if (e >= E) return;
    float r = ew[e];
    if (!(r < CUTOFF_F)) return;
    float C = 0.5f * (cosf(r * PI_OVER_CUTOFF) + 1.0f);
    int src = ei[e];
    int dst = ei[E + e];
    int zt  = z[dst];
    int p = atomicAdd(&woff[src], 1);
    desc[p] = src | (zt << 20);
    cCA[p]  = C;
    eidA[p] = e;
}

// ======================= tier-1 gather: streaming MFMA =======================
// A (packed slots, CSR order) @ B ([dpw|dpb|0] 64x128) -> W, per 16-edge tile.
// Transpose W through per-wave LDS; lane owns h={2l,2l+1}; run-merge over the
// wave's 128 consecutive edges; plain store for complete rows else atomics.
__global__ __launch_bounds__(256) void gather_mfma(
    const int* __restrict__ rowptr, const int* __restrict__ desc,
    const unsigned int* __restrict__ slots, const float* __restrict__ emb,
    const float* __restrict__ dpw, const float* __restrict__ dpb,
    float* __restrict__ agg, int N)
{
    __shared__ float Wlds[4][16 * 132];   // per-wave W tile; also B staging
    int M = rowptr[N];

    // bijective XCD-chunk swizzle
    int nwg = gridDim.x, orig = blockIdx.x;
    int q = nwg >> 3, r8 = nwg & 7, xcd = orig & 7, sub = orig >> 3;
    int lb = (xcd < r8) ? xcd * (q + 1) + sub
                        : r8 * (q + 1) + (xcd - r8) * q + sub;
    int gbase = lb * EPB;
    if (gbase >= M) return;

    int tid  = threadIdx.x;
    int w    = tid >> 6;
    int lane = tid & 63;
    int c    = lane & 15;
    int g    = lane >> 4;

    // stage B into LDS (pitch 36 u32), rows k>=50: dpb at 50, zeros after
    unsigned int* bstage = (unsigned int*)&Wlds[0][0];
    for (int idx = tid; idx < 128 * 32; idx += 256) {
        int h = idx >> 5, p = idx & 31;
        unsigned int u = 0u;
        if (p < 25) {
            float2 v = *(const float2*)(dpw + h * NRBF + 2 * p);
            u = pkh(v.x, v.y);
        } else if (p == 25) {
            u = pkh(dpb[h], 0.f);
        }
        bstage[h * 36 + p] = u;
    }
    __syncthreads();
    half8_t bfrag[8][2];
#pragma unroll
    for (int nt = 0; nt < 8; ++nt)
#pragma unroll
        for (int ks = 0; ks < 2; ++ks) {
            uint4 bu = *(const uint4*)&bstage[(nt * 16 + c) * 36 + ks * 16 + g * 4];
            bfrag[nt][ks] = __builtin_bit_cast(half8_t, bu);
        }
    __syncthreads();                       // done with staging region

    float* Ww = &Wlds[w][0];
    int wbeg = gbase + w * 128;
    int wend = min(wbeg + 128, M);
    if (wbeg >= M) return;

    int   cur = -1, run_start = wbeg;
    float r0 = 0.f, r1 = 0.f;

    for (int tt = 0; tt < 8; ++tt) {
        int eb = wbeg + tt * 16;
        if (eb >= M) break;
        // ---- A fragments: fully coalesced from packed slots ----
        int ge = eb + c;
        const uint4* sp = (const uint4*)(slots + (size_t)ge * SLOT_U32);
        uint4 a0u = make_uint4(0u, 0u, 0u, 0u), a1u = a0u;
        if (ge < M) {
            a0u = sp[g];                               // words g*4..g*4+3
            if (g < 3) a1u = sp[4 + g];                // words 16+g*4..
        }
        half8_t A0 = __builtin_bit_cast(half8_t, a0u);
        half8_t A1 = __builtin_bit_cast(half8_t, a1u);

        f32x4_t acc[8];
#pragma unroll
        for (int nt = 0; nt < 8; ++nt) acc[nt] = (f32x4_t){0.f, 0.f, 0.f, 0.f};
#pragma unroll
        for (int nt = 0; nt < 8; ++nt) {
            acc[nt] = __builtin_amdgcn_mfma_f32_16x16x32_f16(A0, bfrag[nt][0], acc[nt], 0, 0, 0);
            acc[nt] = __builtin_amdgcn_mfma_f32_16x16x32_f16(A1, bfrag[nt][1], acc[nt], 0, 0, 0);
        }
        // ---- transpose W into LDS: row = edge (g*4+r), col = h (nt*16+c) ----
#pragma unroll
        for (int nt = 0; nt < 8; ++nt)
#pragma unroll
            for (int r = 0; r < 4; ++r)
                Ww[(g * 4 + r) * 132 + nt * 16 + c] = acc[nt][r];

        // ---- epilogue: lane owns h-pair 2*lane; serial over 16 edges ----
        for (int e2 = 0; e2 < 16; ++e2) {
            int gi = eb + e2;
            if (gi >= M) break;
            int d   = desc[gi];                        // wave-uniform -> s_load
            int src = d & 0xFFFFF;
            int zt  = (unsigned int)d >> 20;
            if (src != cur) {
                if (cur >= 0) {
                    int rp0 = rowptr[cur], rp1 = rowptr[cur + 1];
                    float* dst = agg + (size_t)cur * HIDDEN + 2 * lane;
                    if (run_start == rp0 && gi == rp1) {
                        *(float2*)dst = make_float2(r0, r1);
                    } else {
                        unsafeAtomicAdd(dst,     r0);
                        unsafeAtomicAdd(dst + 1, r1);
                    }
                }
                cur = src; run_start = gi; r0 = 0.f; r1 = 0.f;
            }
            float2 wv = *(const float2*)&Ww[e2 * 132 + 2 * lane];
            float2 ev = *(const float2*)(emb + (size_t)zt * HIDDEN + 2 * lane);
            r0 = fmaf(wv.x, ev.x, r0);
            r1 = fmaf(wv.y, ev.y, r1);
        }
    }
    if (cur >= 0) {
        int rp0 = rowptr[cur], rp1 = rowptr[cur + 1];
        float* dst = agg + (size_t)cur * HIDDEN + 2 * lane;
        if (run_start == rp0 && wend == rp1) {
            *(float2*)dst = make_float2(r0, r1);
        } else {
            unsafeAtomicAdd(dst,     r0);
            unsafeAtomicAdd(dst + 1, r1);
        }
    }
}

// ======================= tier-2 gather: VALU streaming (R4-proven) =======================
__global__ __launch_bounds__(256) void gather_stream(
    const int* __restrict__ rowptr, const int* __restrict__ desc,
    const float* __restrict__ cC, const int* __restrict__ eidA,
    const float* __restrict__ ea, const float* __restrict__ emb,
    const float* __restrict__ dpw, const float* __restrict__ dpb,
    float* __restrict__ agg, int N, int nwaves)
{
    __shared__ unsigned int sh_ea[4][4][32];
    int lane  = threadIdx.x & 63;
    int wslot = threadIdx.x >> 6;
    int wid = __builtin_amdgcn_readfirstlane((int)((blockIdx.x * blockDim.x + threadIdx.x) >> 6));

    hf2 whA[25], whB[25];
    {
        const float* wr0 = dpw + (size_t)(2 * lane) * NRBF;
        const float* wr1 = wr0 + NRBF;
#pragma unroll
        for (int q = 0; q < 25; ++q) {
            float2 x = *(const float2*)(wr0 + 2 * q);
            float2 y = *(const float2*)(wr1 + 2 * q);
            whA[q] = __builtin_bit_cast(hf2, pkh(x.x, x.y));
            whB[q] = __builtin_bit_cast(hf2, pkh(y.x, y.y));
        }
    }
    float2 db = *(const float2*)(dpb + 2 * lane);

    int M  = rowptr[N];
    int CH = (M + nwaves - 1) / nwaves;
    int c0 = min(wid * CH, M);
    int c1 = min(c0 + CH, M);

    int   cur = -1, run_start = c0;
    float a0 = 0.f, a1 = 0.f;

    for (int i = c0; i < c1; i += 4) {
        int sv[4]; float cf[4]; int ed[4]; float2 ev[4]; float2 eaf[4];
#pragma unroll
        for (int j = 0; j < 4; ++j)
            if (i + j < c1) { sv[j] = desc[i + j]; cf[j] = cC[i + j]; ed[j] = eidA[i + j]; }
#pragma unroll
        for (int j = 0; j < 4; ++j)
            if (i + j < c1) ev[j] = *(const float2*)(emb + (size_t)((unsigned int)sv[j] >> 20) * HIDDEN + 2 * lane);
#pragma unroll
        for (int j = 0; j < 4; ++j)
            if (i + j < c1 && lane < 25) eaf[j] = *(const float2*)(ea + (size_t)ed[j] * NRBF + 2 * lane);
#pragma unroll
        for (int j = 0; j < 4; ++j)
            if (i + j < c1 && lane < 28) {
                unsigned int u = 0u;
                if (lane < 25) u = pkh(eaf[j].x, eaf[j].y);
                sh_ea[wslot][j][lane] = u;
            }
#pragma unroll
        for (int j = 0; j < 4; ++j) {
            if (i + j >= c1) break;
            int src = sv[j] & 0xFFFFF;
            if (src != cur) {
                if (cur >= 0) {
                    int rp0 = rowptr[cur], rp1 = rowptr[cur + 1];
                    float* dst = agg + (size_t)cur * HIDDEN + 2 * lane;
                    if (run_start == rp0 && (i + j) == rp1) {
                        *(float2*)dst = make_float2(a0, a1);
                    } else {
                        unsafeAtomicAdd(dst, a0);
                        unsafeAtomicAdd(dst + 1, a1);
                    }
                }
                cur = src; run_start = i + j; a0 = 0.f; a1 = 0.f;
            }
            float s0 = 0.f, s1 = 0.f;
#pragma unroll
            for (int qq = 0; qq < 6; ++qq) {
                uint4 u = *(const uint4*)&sh_ea[wslot][j][qq * 4];
#pragma unroll
                for (int t = 0; t < 4; ++t) {
                    unsigned int ww = (t == 0) ? u.x : (t == 1) ? u.y : (t == 2) ? u.z : u.w;
                    hf2 e2 = __builtin_bit_cast(hf2, ww);
#ifdef __has_builtin
#if __has_builtin(__builtin_amdgcn_fdot2)
                    s0 = __builtin_amdgcn_fdot2(e2, whA[qq * 4 + t], s0, false);
                    s1 = __builtin_amdgcn_fdot2(e2, whB[qq * 4 + t], s1, false);
#else
                    s0 = fmaf((float)e2[0], (float)whA[qq*4+t][0], fmaf((float)e2[1], (float)whA[qq*4+t][1], s0));
                    s1 = fmaf((float)e2[0], (float)whB[qq*4+t][0], fmaf((float)e2[1], (float)whB[qq*4+t][1], s1));
#endif
#endif
                }
            }
            {
                hf2 e2 = __builtin_bit_cast(hf2, sh_ea[wslot][j][24]);
                s0 = fmaf((float)e2[0], (float)whA[24][0], fmaf((float)e2[1], (float)whA[24][1], s0));
                s1 = fmaf((float)e2[0], (float)whB[24][0], fmaf((float)e2[1], (float)whB[24][1], s1));
            }
            float W0 = (s0 + db.x) * cf[j];
            float W1 = (s1 + db.y) * cf[j];
            a0 = fmaf(W0, ev[j].x, a0);
            a1 = fmaf(W1, ev[j].y, a1);
        }
    }
    if (cur >= 0) {
        int rp0 = rowptr[cur], rp1 = rowptr[cur + 1];
        float* dst = agg + (size_t)cur * HIDDEN + 2 * lane;
        if (run_start == rp0 && c1 == rp1) {
            *(float2*)dst = make_float2(a0, a1);
        } else {
            unsafeAtomicAdd(dst, a0);
            unsafeAtomicAdd(dst + 1, a1);
        }
    }
}

// ======================= tier-3 fallback =======================
__global__ __launch_bounds__(256) void edge_kernel(
    const int* __restrict__ z, const int* __restrict__ ei,
    const float* __restrict__ ew, const float* __restrict__ ea,
    const float* __restrict__ emb, const float* __restrict__ dpw,
    const float* __restrict__ dpb, float* __restrict__ agg, int E)
{
    int e = blockIdx.x * 256 + threadIdx.x;
    if (e >= E) return;
    float r = ew[e];
    if (!(r < CUTOFF_F)) return;
    float C = 0.5f * (cosf(r * PI_OVER_CUTOFF) + 1.0f);
    int src = ei[e];
    int dst = ei[E + e];
    int zt  = z[dst];
    float av[NRBF];
#pragma unroll
    for (int k = 0; k < NRBF; ++k) av[k] = ea[(size_t)e * NRBF + k];
    const float* er = emb + (size_t)zt * HIDDEN;
    float*       ar = agg + (size_t)src * HIDDEN;
#pragma unroll 2
    for (int h = 0; h < HIDDEN; ++h) {
        const float* wrow = dpw + h * NRBF;
        float s0 = 0.f, s1 = 0.f;
#pragma unroll
        for (int k = 0; k < NRBF; k += 2) {
            s0 = fmaf(av[k],     wrow[k],     s0);
            s1 = fmaf(av[k + 1], wrow[k + 1], s1);
        }
        float w2 = (dpb[h] + s0 + s1) * C;
        unsafeAtomicAdd(&ar[h], w2 * er[h]);
    }
}

// ======================= Combine: bf16 MFMA GEMM =======================
__global__ __launch_bounds__(256) void combine_mfma(
    const float* __restrict__ nf, const float* __restrict__ cw,
    const float* __restrict__ cbias, float* out, int N)
{
    __shared__ unsigned int As_u[64 * 20];
    __shared__ unsigned int Bs_u[128 * 20];
    int tid  = threadIdx.x;
    int w    = tid >> 6;
    int lane = tid & 63;
    int c    = lane & 15;
    int g    = lane >> 4;
    int row0 = blockIdx.x * 64;

    f32x4_t acc[8];
#pragma unroll
    for (int q = 0; q < 8; ++q) acc[q] = (f32x4_t){0.f, 0.f, 0.f, 0.f};

    for (int ks = 0; ks < 8; ++ks) {
        const float* src = (ks < 4) ? nf : out;
        int kb = (ks & 3) * 32;
        {
            int r = tid >> 2, kq = tid & 3;
            int row = row0 + r;
            float4 v0 = make_float4(0.f, 0.f, 0.f, 0.f), v1 = v0;
            if (row < N) {
                const float4* p = (const float4*)(src + (size_t)row * HIDDEN + kb + kq * 8);
                v0 = p[0]; v1 = p[1];
            }
            *(uint4*)&As_u[r * 20 + kq * 4] =
                make_uint4(pk_bf16(v0.x, v0.y), pk_bf16(v0.z, v0.w),
                           pk_bf16(v1.x, v1.y), pk_bf16(v1.z, v1.w));
        }
        {
            int j = tid >> 1, hf = tid & 1;
            const float4* p = (const float4*)(cw + (size_t)j * 256 + ks * 32 + hf * 16);
            float4 b0 = p[0], b1 = p[1], b2 = p[2], b3 = p[3];
            *(uint4*)&Bs_u[j * 20 + hf * 8] =
                make_uint4(pk_bf16(b0.x, b0.y), pk_bf16(b0.z, b0.w),
                           pk_bf16(b1.x, b1.y), pk_bf16(b1.z, b1.w));
            *(uint4*)&Bs_u[j * 20 + hf * 8 + 4] =
                make_uint4(pk_bf16(b2.x, b2.y), pk_bf16(b2.z, b2.w),
                           pk_bf16(b3.x, b3.y), pk_bf16(b3.z, b3.w));
        }
        __syncthreads();
        uint4 au = *(const uint4*)&As_u[(w * 16 + c) * 20 + g * 4];
        short8_t af = __builtin_bit_cast(short8_t, au);
#pragma unroll
        for (int cbk = 0; cbk < 8; ++cbk) {
            uint4 bu = *(const uint4*)&Bs_u[(cbk * 16 + c) * 20 + g * 4];
            short8_t bf = __builtin_bit_cast(short8_t, bu);
            acc[cbk] = __builtin_amdgcn_mfma_f32_16x16x32_bf16(af, bf, acc[cbk], 0, 0, 0);
        }
        __syncthreads();
    }
#pragma unroll
    for (int cbk = 0; cbk < 8; ++cbk) {
        float bias = cbias[cbk * 16 + c];
#pragma unroll
        for (int r = 0; r < 4; ++r) {
            int row = row0 + w * 16 + g * 4 + r;
            if (row < N) out[(size_t)row * HIDDEN + cbk * 16 + c] = acc[cbk][r] + bias;
        }
    }
}

// ======================= launch =======================

extern "C" void kernel_launch(void* const* d_in, const int* in_sizes, int n_in,
                              void* d_out, int out_size, void* d_ws, size_t ws_size,
                              hipStream_t stream)
{
    const int*   z   = (const int*)  d_in[0];
    const float* nf  = (const float*)d_in[1];
    const int*   ei  = (const int*)  d_in[2];
    const float* ew  = (const float*)d_in[3];
    const float* ea  = (const float*)d_in[4];
    const float* emb = (const float*)d_in[5];
    const float* dpw = (const float*)d_in[6];
    const float* dpb = (const float*)d_in[7];
    const float* cw  = (const float*)d_in[8];
    const float* cb  = (const float*)d_in[9];
    float* out = (float*)d_out;

    int N = in_sizes[0];
    int E = in_sizes[3];

    size_t hdr  = ((size_t)2 * N + 1 + 1024 + 3) & ~(size_t)3;        // u32s
    size_t need1 = (hdr + (size_t)E + (size_t)E * SLOT_U32 + 4) * 4;  // tier 1
    size_t need2 = (hdr + (size_t)3 * E) * 4;                         // tier 2

    (void)hipMemsetAsync(out, 0, (size_t)N * HIDDEN * sizeof(float), stream);

    int nb1 = (N + 1023) / 1024;

    if (ws_size >= need1) {
        int* rowptr = (int*)d_ws;
        int* woff   = rowptr + (N + 1);
        int* bsum   = woff + N;
        int* desc   = (int*)d_ws + hdr;
        unsigned int* slots = (unsigned int*)(desc + E);
        // align slots to 16B
        slots = (unsigned int*)(((size_t)slots + 15) & ~(size_t)15);

        (void)hipMemsetAsync(woff, 0, (size_t)N * 4, stream);
        hist_kernel<<<(E + 255) / 256, 256, 0, stream>>>(ei, ew, woff, E);
        scan1_kernel<<<nb1, 256, 0, stream>>>(woff, rowptr, bsum, N);
        scan2_kernel<<<1, 256, 0, stream>>>(bsum, rowptr, nb1, N);
        scan3_kernel<<<nb1, 256, 0, stream>>>(rowptr, woff, bsum, N);
        scatter_pack<<<(E + 255) / 256, 256, 0, stream>>>(z, ei, ew, ea, woff,
                                                          desc, slots, E);
        int nblk = (E + EPB - 1) / EPB;
        gather_mfma<<<nblk, 256, 0, stream>>>(rowptr, desc, slots, emb,
                                              dpw, dpb, out, N);
    } else if (ws_size >= need2) {
        int* rowptr = (int*)d_ws;
        int* woff   = rowptr + (N + 1);
        int* bsum   = woff + N;
        int* desc   = (int*)d_ws + hdr;
        float* cCA  = (float*)(desc + E);
        int* eidA   = (int*)(cCA + E);

        (void)hipMemsetAsync(woff, 0, (size_t)N * 4, stream);
        hist_kernel<<<(E + 255) / 256, 256, 0, stream>>>(ei, ew, woff, E);
        scan1_kernel<<<nb1, 256, 0, stream>>>(woff, rowptr, bsum, N);
        scan2_kernel<<<1, 256, 0, stream>>>(bsum, rowptr, nb1, N);
        scan3_kernel<<<nb1, 256, 0, stream>>>(rowptr, woff, bsum, N);
        scatter_simple<<<(E + 255) / 256, 256, 0, stream>>>(z, ei, ew, woff,
                                                            desc, cCA, eidA, E);
        const int blocks = 2048;
        gather_stream<<<blocks, 256, 0, stream>>>(rowptr, desc, cCA, eidA,
                                                  ea, emb, dpw, dpb, out, N,
                                                  blocks * 4);
    } else {
        edge_kernel<<<(E + 255) / 256, 256, 0, stream>>>(z, ei, ew, ea, emb,
                                                         dpw, dpb, out, E);
    }

    combine_mfma<<<(N + 63) / 64, 256, 0, stream>>>(nf, cw, cb, out, N);
}

// Round 8
// 452.149 us; speedup vs baseline: 1.5381x; 1.2478x over previous
//
#include <hip/hip_runtime.h>

#define HIDDEN 128
#define NRBF 50
#define CUTOFF_F 5.0f
#define PI_OVER_CUTOFF 0.6283185307179586f
#define SLOT_U32 28      // 112B packed A-row per live edge
#define EPB 512          // edges per block in gather (4 waves x 128)

typedef _Float16 half8_t __attribute__((ext_vector_type(8)));
using f32x4_t  = __attribute__((ext_vector_type(4))) float;
using short8_t = __attribute__((ext_vector_type(8))) short;
typedef __attribute__((ext_vector_type(2))) _Float16 hf2;

static __device__ __forceinline__ unsigned int pkh(float a, float b) {
    return __builtin_bit_cast(unsigned int, __builtin_amdgcn_cvt_pkrtz(a, b));
}
static __device__ __forceinline__ unsigned int pk_bf16(float a, float b) {
    unsigned int ua = __float_as_uint(a), ub = __float_as_uint(b);
    ua = (ua + 0x7FFFu + ((ua >> 16) & 1u)) >> 16;
    ub = (ub + 0x7FFFu + ((ub >> 16) & 1u)) >> 16;
    return ua | (ub << 16);
}

// ======================= CSR build =======================

__global__ __launch_bounds__(256) void hist_kernel(
    const int* __restrict__ ei, const float* __restrict__ ew,
    int* __restrict__ cnt, int E)
{
    int e = blockIdx.x * 256 + threadIdx.x;
    if (e >= E) return;
    float r = ew[e];
    if (r < CUTOFF_F) atomicAdd(&cnt[ei[e]], 1);
}

__global__ __launch_bounds__(256) void scan1_kernel(
    const int* __restrict__ cnt, int* __restrict__ rowptr,
    int* __restrict__ bsum, int N)
{
    __shared__ int sh[256];
    int t = threadIdx.x, b = blockIdx.x;
    int base = b * 1024 + t * 4;
    int v[4];
#pragma unroll
    for (int j = 0; j < 4; ++j) v[j] = (base + j < N) ? cnt[base + j] : 0;
    int s = v[0] + v[1] + v[2] + v[3];
    sh[t] = s;
    __syncthreads();
    for (int off = 1; off < 256; off <<= 1) {
        int x = (t >= off) ? sh[t - off] : 0;
        __syncthreads();
        sh[t] += x;
        __syncthreads();
    }
    int run = sh[t] - s;
#pragma unroll
    for (int j = 0; j < 4; ++j) {
        if (base + j < N) rowptr[base + j] = run;
        run += v[j];
    }
    if (t == 255) bsum[b] = sh[255];
}

__global__ __launch_bounds__(256) void scan2_kernel(
    int* __restrict__ bsum, int* __restrict__ rowptr, int nb, int N)
{
    __shared__ int sh[256];
    int t = threadIdx.x;
    int v = (t < nb) ? bsum[t] : 0;
    sh[t] = v;
    __syncthreads();
    for (int off = 1; off < 256; off <<= 1) {
        int x = (t >= off) ? sh[t - off] : 0;
        __syncthreads();
        sh[t] += x;
        __syncthreads();
    }
    if (t < nb) bsum[t] = sh[t] - v;
    if (t == 255) rowptr[N] = sh[255];
}

__global__ __launch_bounds__(256) void scan3_kernel(
    int* __restrict__ rowptr, int* __restrict__ woff,
    const int* __restrict__ bsum, int N)
{
    int t = threadIdx.x, b = blockIdx.x;
    int base = b * 1024 + t * 4;
    int off = bsum[b];
#pragma unroll
    for (int j = 0; j < 4; ++j) {
        int i = base + j;
        if (i < N) {
            int r = rowptr[i] + off;
            rowptr[i] = r;
            woff[i] = r;
        }
    }
}

// zero the pad region [M, M+512) of desc and slots so gather needs no guards
__global__ __launch_bounds__(256) void pad_kernel(
    const int* __restrict__ rowptr, int N,
    int* __restrict__ desc, unsigned int* __restrict__ slots)
{
    int M = rowptr[N];
    int t = blockIdx.x * 256 + threadIdx.x;
    for (int i = t; i < 512; i += 256 * gridDim.x) desc[M + i] = 0;
    for (int i = t; i < 512 * SLOT_U32; i += 256 * gridDim.x)
        slots[(size_t)M * SLOT_U32 + i] = 0u;
}

// tier-1 scatter: CSR-reorder + pre-pack A-row (C*ea | C | 0) as f16, 112B
__global__ __launch_bounds__(256) void scatter_pack(
    const int* __restrict__ z, const int* __restrict__ ei,
    const float* __restrict__ ew, const float* __restrict__ ea,
    int* __restrict__ woff, int* __restrict__ desc,
    unsigned int* __restrict__ slots, int E)
{
    int e = blockIdx.x * 256 + threadIdx.x;
    if (e >= E) return;
    float r = ew[e];
    if (!(r < CUTOFF_F)) return;
    float C = 0.5f * (cosf(r * PI_OVER_CUTOFF) + 1.0f);
    int src = ei[e];
    int dst = ei[E + e];
    int zt  = z[dst];
    int p = atomicAdd(&woff[src], 1);
    desc[p] = src | (zt << 20);

    unsigned int buf[SLOT_U32];
    const float2* rp = (const float2*)(ea + (size_t)e * NRBF);
#pragma unroll
    for (int q = 0; q < 25; ++q) {
        float2 v = rp[q];
        buf[q] = pkh(C * v.x, C * v.y);
    }
    buf[25] = pkh(C, 0.f);
    buf[26] = 0u; buf[27] = 0u;
    uint4* sp = (uint4*)(slots + (size_t)p * SLOT_U32);
#pragma unroll
    for (int q = 0; q < 7; ++q) sp[q] = ((const uint4*)buf)[q];
}

// tier-2 scatter: descriptors only
__global__ __launch_bounds__(256) void scatter_simple(
    const int* __restrict__ z, const int* __restrict__ ei,
    const float* __restrict__ ew, int* __restrict__ woff,
    int* __restrict__ desc, float* __restrict__ cCA, int* __restrict__ eidA,
    int E)
{
    int e = blockIdx.x * 256 + threadIdx.x;
    if (e >= E) return;
    float r = ew[e];
    if (!(r < CUTOFF_F)) return;
    float C = 0.5f * (cosf(r * PI_OVER_CUTOFF) + 1.0f);
    int src = ei[e];
    int dst = ei[E + e];
    int zt  = z[dst];
    int p = atomicAdd(&woff[src], 1);
    desc[p] = src | (zt << 20);
    cCA[p]  = C;
    eidA[p] = e;
}

// ======================= tier-1 gather: streaming MFMA, pipelined =======================
// Guard-free (pad region zeroed). Per tile: prefetch next A, batch-load descs
// (scalar) + 16 emb rows, MFMA, transpose W through per-wave LDS, register
// run-merge. Completeness of a run derived from desc alone (no rowptr reads).
__global__ __launch_bounds__(256) void gather_mfma(
    const int* __restrict__ rowptr, const int* __restrict__ desc,
    const unsigned int* __restrict__ slots, const float* __restrict__ emb,
    const float* __restrict__ dpw, const float* __restrict__ dpb,
    float* __restrict__ agg, int N)
{
    __shared__ float Wlds[4][16 * 132];   // per-wave W tile; [0] doubles as B staging
    int M = rowptr[N];

    // bijective XCD-chunk swizzle
    int nwg = gridDim.x, orig = blockIdx.x;
    int q = nwg >> 3, r8 = nwg & 7, xcd = orig & 7, sub = orig >> 3;
    int lb = (xcd < r8) ? xcd * (q + 1) + sub
                        : r8 * (q + 1) + (xcd - r8) * q + sub;
    int gbase = lb * EPB;
    if (gbase >= M) return;

    int tid  = threadIdx.x;
    int w    = tid >> 6;
    int lane = tid & 63;
    int c    = lane & 15;
    int g    = lane >> 4;

    // stage B into LDS (pitch 36 u32)
    unsigned int* bstage = (unsigned int*)&Wlds[0][0];
    for (int idx = tid; idx < 128 * 32; idx += 256) {
        int h = idx >> 5, p = idx & 31;
        unsigned int u = 0u;
        if (p < 25) {
            float2 v = *(const float2*)(dpw + h * NRBF + 2 * p);
            u = pkh(v.x, v.y);
        } else if (p == 25) {
            u = pkh(dpb[h], 0.f);
        }
        bstage[h * 36 + p] = u;
    }
    __syncthreads();
    half8_t bfrag[8][2];
#pragma unroll
    for (int nt = 0; nt < 8; ++nt)
#pragma unroll
        for (int ks = 0; ks < 2; ++ks) {
            uint4 bu = *(const uint4*)&bstage[(nt * 16 + c) * 36 + ks * 16 + g * 4];
            bfrag[nt][ks] = __builtin_bit_cast(half8_t, bu);
        }
    __syncthreads();                       // staging region now reusable as W

    float* Ww = &Wlds[w][0];
    int wbeg = gbase + w * 128;
    if (wbeg >= M) return;

    // first-run-start completeness from the previous edge's src
    bool runc;
    if (wbeg == 0) runc = true;
    else runc = ((desc[wbeg - 1] & 0xFFFFF) != (desc[wbeg] & 0xFFFFF));

    const int4* dp = (const int4*)(desc + wbeg);

    // prefetch tile 0
    const uint4* sp0 = (const uint4*)(slots + (size_t)(wbeg + c) * SLOT_U32);
    uint4 a0c = sp0[g];
    uint4 a1c = (g < 3) ? sp0[4 + g] : make_uint4(0u, 0u, 0u, 0u);
    int4 d0 = dp[0], d1 = dp[1], d2 = dp[2], d3 = dp[3];

    int   cur = -1;
    float r0 = 0.f, r1 = 0.f;

    for (int t = 0; t < 8; ++t) {
        int eb = wbeg + t * 16;
        // current tile regs
        uint4 A0u = a0c, A1u = a1c;
        int s_[16];
        s_[0]=d0.x;  s_[1]=d0.y;  s_[2]=d0.z;  s_[3]=d0.w;
        s_[4]=d1.x;  s_[5]=d1.y;  s_[6]=d1.z;  s_[7]=d1.w;
        s_[8]=d2.x;  s_[9]=d2.y;  s_[10]=d2.z; s_[11]=d2.w;
        s_[12]=d3.x; s_[13]=d3.y; s_[14]=d3.z; s_[15]=d3.w;

        // prefetch next tile (pad guarantees validity)
        if (t < 7) {
            const uint4* spn = (const uint4*)(slots + (size_t)(eb + 16 + c) * SLOT_U32);
            a0c = spn[g];
            a1c = (g < 3) ? spn[4 + g] : make_uint4(0u, 0u, 0u, 0u);
            d0 = dp[t * 4 + 4]; d1 = dp[t * 4 + 5];
            d2 = dp[t * 4 + 6]; d3 = dp[t * 4 + 7];
        }

        // batch emb loads for all 16 edges (independent, all in flight)
        float2 ev[16];
#pragma unroll
        for (int e2 = 0; e2 < 16; ++e2)
            ev[e2] = *(const float2*)(emb + (size_t)((unsigned int)s_[e2] >> 20) * HIDDEN + 2 * lane);

        // MFMA
        half8_t A0 = __builtin_bit_cast(half8_t, A0u);
        half8_t A1 = __builtin_bit_cast(half8_t, A1u);
        f32x4_t acc[8];
#pragma unroll
        for (int nt = 0; nt < 8; ++nt) acc[nt] = (f32x4_t){0.f, 0.f, 0.f, 0.f};
#pragma unroll
        for (int nt = 0; nt < 8; ++nt) {
            acc[nt] = __builtin_amdgcn_mfma_f32_16x16x32_f16(A0, bfrag[nt][0], acc[nt], 0, 0, 0);
            acc[nt] = __builtin_amdgcn_mfma_f32_16x16x32_f16(A1, bfrag[nt][1], acc[nt], 0, 0, 0);
        }
        // transpose W into per-wave LDS: row = edge (g*4+r), col = h
#pragma unroll
        for (int nt = 0; nt < 8; ++nt)
#pragma unroll
            for (int r = 0; r < 4; ++r)
                Ww[(g * 4 + r) * 132 + nt * 16 + c] = acc[nt][r];

        // register run-merge over 16 edges (pure VALU + LDS reads)
#pragma unroll
        for (int e2 = 0; e2 < 16; ++e2) {
            int d   = s_[e2];
            int src = d & 0xFFFFF;
            if (src != cur) {
                if (cur >= 0) {
                    float* dst = agg + (size_t)cur * HIDDEN + 2 * lane;
                    if (runc) {
                        *(float2*)dst = make_float2(r0, r1);
                    } else {
                        unsafeAtomicAdd(dst,     r0);
                        unsafeAtomicAdd(dst + 1, r1);
                    }
                    runc = true;           // later runs start at a row start
                }
                cur = src; r0 = 0.f; r1 = 0.f;
            }
            float2 wv = *(const float2*)&Ww[e2 * 132 + 2 * lane];
            r0 = fmaf(wv.x, ev[e2].x, r0);
            r1 = fmaf(wv.y, ev[e2].y, r1);
        }
    }
    // final flush: end-complete iff next edge has a different src
    if (cur >= 0) {
        int nxt = desc[wbeg + 128] & 0xFFFFF;     // pad makes this valid
        float* dst = agg + (size_t)cur * HIDDEN + 2 * lane;
        if (runc && nxt != cur) {
            *(float2*)dst = make_float2(r0, r1);
        } else {
            unsafeAtomicAdd(dst,     r0);
            unsafeAtomicAdd(dst + 1, r1);
        }
    }
}

// ======================= tier-2 gather: VALU streaming =======================
__global__ __launch_bounds__(256) void gather_stream(
    const int* __restrict__ rowptr, const int* __restrict__ desc,
    const float* __restrict__ cC, const int* __restrict__ eidA,
    const float* __restrict__ ea, const float* __restrict__ emb,
    const float* __restrict__ dpw, const float* __restrict__ dpb,
    float* __restrict__ agg, int N, int nwaves)
{
    __shared__ unsigned int sh_ea[4][4][32];
    int lane  = threadIdx.x & 63;
    int wslot = threadIdx.x >> 6;
    int wid = __builtin_amdgcn_readfirstlane((int)((blockIdx.x * blockDim.x + threadIdx.x) >> 6));

    hf2 whA[25], whB[25];
    {
        const float* wr0 = dpw + (size_t)(2 * lane) * NRBF;
        const float* wr1 = wr0 + NRBF;
#pragma unroll
        for (int q = 0; q < 25; ++q) {
            float2 x = *(const float2*)(wr0 + 2 * q);
            float2 y = *(const float2*)(wr1 + 2 * q);
            whA[q] = __builtin_bit_cast(hf2, pkh(x.x, x.y));
            whB[q] = __builtin_bit_cast(hf2, pkh(y.x, y.y));
        }
    }
    float2 db = *(const float2*)(dpb + 2 * lane);

    int M  = rowptr[N];
    int CH = (M + nwaves - 1) / nwaves;
    int c0 = min(wid * CH, M);
    int c1 = min(c0 + CH, M);

    int   cur = -1, run_start = c0;
    float a0 = 0.f, a1 = 0.f;

    for (int i = c0; i < c1; i += 4) {
        int sv[4]; float cf[4]; int ed[4]; float2 ev[4]; float2 eaf[4];
#pragma unroll
        for (int j = 0; j < 4; ++j)
            if (i + j < c1) { sv[j] = desc[i + j]; cf[j] = cC[i + j]; ed[j] = eidA[i + j]; }
#pragma unroll
        for (int j = 0; j < 4; ++j)
            if (i + j < c1) ev[j] = *(const float2*)(emb + (size_t)((unsigned int)sv[j] >> 20) * HIDDEN + 2 * lane);
#pragma unroll
        for (int j = 0; j < 4; ++j)
            if (i + j < c1 && lane < 25) eaf[j] = *(const float2*)(ea + (size_t)ed[j] * NRBF + 2 * lane);
#pragma unroll
        for (int j = 0; j < 4; ++j)
            if (i + j < c1 && lane < 28) {
                unsigned int u = 0u;
                if (lane < 25) u = pkh(eaf[j].x, eaf[j].y);
                sh_ea[wslot][j][lane] = u;
            }
#pragma unroll
        for (int j = 0; j < 4; ++j) {
            if (i + j >= c1) break;
            int src = sv[j] & 0xFFFFF;
            if (src != cur) {
                if (cur >= 0) {
                    int rp0 = rowptr[cur], rp1 = rowptr[cur + 1];
                    float* dst = agg + (size_t)cur * HIDDEN + 2 * lane;
                    if (run_start == rp0 && (i + j) == rp1) {
                        *(float2*)dst = make_float2(a0, a1);
                    } else {
                        unsafeAtomicAdd(dst, a0);
                        unsafeAtomicAdd(dst + 1, a1);
                    }
                }
                cur = src; run_start = i + j; a0 = 0.f; a1 = 0.f;
            }
            float s0 = 0.f, s1 = 0.f;
#pragma unroll
            for (int qq = 0; qq < 6; ++qq) {
                uint4 u = *(const uint4*)&sh_ea[wslot][j][qq * 4];
#pragma unroll
                for (int t = 0; t < 4; ++t) {
                    unsigned int ww = (t == 0) ? u.x : (t == 1) ? u.y : (t == 2) ? u.z : u.w;
                    hf2 e2 = __builtin_bit_cast(hf2, ww);
                    s0 = fmaf((float)e2[0], (float)whA[qq*4+t][0], fmaf((float)e2[1], (float)whA[qq*4+t][1], s0));
                    s1 = fmaf((float)e2[0], (float)whB[qq*4+t][0], fmaf((float)e2[1], (float)whB[qq*4+t][1], s1));
                }
            }
            {
                hf2 e2 = __builtin_bit_cast(hf2, sh_ea[wslot][j][24]);
                s0 = fmaf((float)e2[0], (float)whA[24][0], fmaf((float)e2[1], (float)whA[24][1], s0));
                s1 = fmaf((float)e2[0], (float)whB[24][0], fmaf((float)e2[1], (float)whB[24][1], s1));
            }
            float W0 = (s0 + db.x) * cf[j];
            float W1 = (s1 + db.y) * cf[j];
            a0 = fmaf(W0, ev[j].x, a0);
            a1 = fmaf(W1, ev[j].y, a1);
        }
    }
    if (cur >= 0) {
        int rp0 = rowptr[cur], rp1 = rowptr[cur + 1];
        float* dst = agg + (size_t)cur * HIDDEN + 2 * lane;
        if (run_start == rp0 && c1 == rp1) {
            *(float2*)dst = make_float2(a0, a1);
        } else {
            unsafeAtomicAdd(dst, a0);
            unsafeAtomicAdd(dst + 1, a1);
        }
    }
}

// ======================= tier-3 fallback =======================
__global__ __launch_bounds__(256) void edge_kernel(
    const int* __restrict__ z, const int* __restrict__ ei,
    const float* __restrict__ ew, const float* __restrict__ ea,
    const float* __restrict__ emb, const float* __restrict__ dpw,
    const float* __restrict__ dpb, float* __restrict__ agg, int E)
{
    int e = blockIdx.x * 256 + threadIdx.x;
    if (e >= E) return;
    float r = ew[e];
    if (!(r < CUTOFF_F)) return;
    float C = 0.5f * (cosf(r * PI_OVER_CUTOFF) + 1.0f);
    int src = ei[e];
    int dst = ei[E + e];
    int zt  = z[dst];
    float av[NRBF];
#pragma unroll
    for (int k = 0; k < NRBF; ++k) av[k] = ea[(size_t)e * NRBF + k];
    const float* er = emb + (size_t)zt * HIDDEN;
    float*       ar = agg + (size_t)src * HIDDEN;
#pragma unroll 2
    for (int h = 0; h < HIDDEN; ++h) {
        const float* wrow = dpw + h * NRBF;
        float s0 = 0.f, s1 = 0.f;
#pragma unroll
        for (int k = 0; k < NRBF; k += 2) {
            s0 = fmaf(av[k],     wrow[k],     s0);
            s1 = fmaf(av[k + 1], wrow[k + 1], s1);
        }
        float w2 = (dpb[h] + s0 + s1) * C;
        unsafeAtomicAdd(&ar[h], w2 * er[h]);
    }
}

// ======================= Combine: bf16 MFMA GEMM =======================
__global__ __launch_bounds__(256) void combine_mfma(
    const float* __restrict__ nf, const float* __restrict__ cw,
    const float* __restrict__ cbias, float* out, int N)
{
    __shared__ unsigned int As_u[64 * 20];
    __shared__ unsigned int Bs_u[128 * 20];
    int tid  = threadIdx.x;
    int w    = tid >> 6;
    int lane = tid & 63;
    int c    = lane & 15;
    int g    = lane >> 4;
    int row0 = blockIdx.x * 64;

    f32x4_t acc[8];
#pragma unroll
    for (int q = 0; q < 8; ++q) acc[q] = (f32x4_t){0.f, 0.f, 0.f, 0.f};

    for (int ks = 0; ks < 8; ++ks) {
        const float* src = (ks < 4) ? nf : out;
        int kb = (ks & 3) * 32;
        {
            int r = tid >> 2, kq = tid & 3;
            int row = row0 + r;
            float4 v0 = make_float4(0.f, 0.f, 0.f, 0.f), v1 = v0;
            if (row < N) {
                const float4* p = (const float4*)(src + (size_t)row * HIDDEN + kb + kq * 8);
                v0 = p[0]; v1 = p[1];
            }
            *(uint4*)&As_u[r * 20 + kq * 4] =
                make_uint4(pk_bf16(v0.x, v0.y), pk_bf16(v0.z, v0.w),
                           pk_bf16(v1.x, v1.y), pk_bf16(v1.z, v1.w));
        }
        {
            int j = tid >> 1, hf = tid & 1;
            const float4* p = (const float4*)(cw + (size_t)j * 256 + ks * 32 + hf * 16);
            float4 b0 = p[0], b1 = p[1], b2 = p[2], b3 = p[3];
            *(uint4*)&Bs_u[j * 20 + hf * 8] =
                make_uint4(pk_bf16(b0.x, b0.y), pk_bf16(b0.z, b0.w),
                           pk_bf16(b1.x, b1.y), pk_bf16(b1.z, b1.w));
            *(uint4*)&Bs_u[j * 20 + hf * 8 + 4] =
                make_uint4(pk_bf16(b2.x, b2.y), pk_bf16(b2.z, b2.w),
                           pk_bf16(b3.x, b3.y), pk_bf16(b3.z, b3.w));
        }
        __syncthreads();
        uint4 au = *(const uint4*)&As_u[(w * 16 + c) * 20 + g * 4];
        short8_t af = __builtin_bit_cast(short8_t, au);
#pragma unroll
        for (int cbk = 0; cbk < 8; ++cbk) {
            uint4 bu = *(const uint4*)&Bs_u[(cbk * 16 + c) * 20 + g * 4];
            short8_t bf = __builtin_bit_cast(short8_t, bu);
            acc[cbk] = __builtin_amdgcn_mfma_f32_16x16x32_bf16(af, bf, acc[cbk], 0, 0, 0);
        }
        __syncthreads();
    }
#pragma unroll
    for (int cbk = 0; cbk < 8; ++cbk) {
        float bias = cbias[cbk * 16 + c];
#pragma unroll
        for (int r = 0; r < 4; ++r) {
            int row = row0 + w * 16 + g * 4 + r;
            if (row < N) out[(size_t)row * HIDDEN + cbk * 16 + c] = acc[cbk][r] + bias;
        }
    }
}

// ======================= launch =======================

extern "C" void kernel_launch(void* const* d_in, const int* in_sizes, int n_in,
                              void* d_out, int out_size, void* d_ws, size_t ws_size,
                              hipStream_t stream)
{
    const int*   z   = (const int*)  d_in[0];
    const float* nf  = (const float*)d_in[1];
    const int*   ei  = (const int*)  d_in[2];
    const float* ew  = (const float*)d_in[3];
    const float* ea  = (const float*)d_in[4];
    const float* emb = (const float*)d_in[5];
    const float* dpw = (const float*)d_in[6];
    const float* dpb = (const float*)d_in[7];
    const float* cw  = (const float*)d_in[8];
    const float* cb  = (const float*)d_in[9];
    float* out = (float*)d_out;

    int N = in_sizes[0];
    int E = in_sizes[3];

    size_t hdr  = ((size_t)2 * N + 1 + 1024 + 3) & ~(size_t)3;             // u32s
    size_t Epad = (size_t)E + 512;
    size_t need1 = (hdr + Epad + Epad * SLOT_U32 + 8) * 4;                 // tier 1
    size_t need2 = (hdr + (size_t)3 * E) * 4;                              // tier 2

    (void)hipMemsetAsync(out, 0, (size_t)N * HIDDEN * sizeof(float), stream);

    int nb1 = (N + 1023) / 1024;

    if (ws_size >= need1) {
        int* rowptr = (int*)d_ws;
        int* woff   = rowptr + (N + 1);
        int* bsum   = woff + N;
        int* desc   = (int*)d_ws + hdr;
        unsigned int* slots = (unsigned int*)(desc + Epad);
        slots = (unsigned int*)(((size_t)slots + 15) & ~(size_t)15);

        (void)hipMemsetAsync(woff, 0, (size_t)N * 4, stream);
        hist_kernel<<<(E + 255) / 256, 256, 0, stream>>>(ei, ew, woff, E);
        scan1_kernel<<<nb1, 256, 0, stream>>>(woff, rowptr, bsum, N);
        scan2_kernel<<<1, 256, 0, stream>>>(bsum, rowptr, nb1, N);
        scan3_kernel<<<nb1, 256, 0, stream>>>(rowptr, woff, bsum, N);
        scatter_pack<<<(E + 255) / 256, 256, 0, stream>>>(z, ei, ew, ea, woff,
                                                          desc, slots, E);
        pad_kernel<<<8, 256, 0, stream>>>(rowptr, N, desc, slots);
        int nblk = (E + EPB - 1) / EPB;
        gather_mfma<<<nblk, 256, 0, stream>>>(rowptr, desc, slots, emb,
                                              dpw, dpb, out, N);
    } else if (ws_size >= need2) {
        int* rowptr = (int*)d_ws;
        int* woff   = rowptr + (N + 1);
        int* bsum   = woff + N;
        int* desc   = (int*)d_ws + hdr;
        float* cCA  = (float*)(desc + E);
        int* eidA   = (int*)(cCA + E);

        (void)hipMemsetAsync(woff, 0, (size_t)N * 4, stream);
        hist_kernel<<<(E + 255) / 256, 256, 0, stream>>>(ei, ew, woff, E);
        scan1_kernel<<<nb1, 256, 0, stream>>>(woff, rowptr, bsum, N);
        scan2_kernel<<<1, 256, 0, stream>>>(bsum, rowptr, nb1, N);
        scan3_kernel<<<nb1, 256, 0, stream>>>(rowptr, woff, bsum, N);
        scatter_simple<<<(E + 255) / 256, 256, 0, stream>>>(z, ei, ew, woff,
                                                            desc, cCA, eidA, E);
        const int blocks = 2048;
        gather_stream<<<blocks, 256, 0, stream>>>(rowptr, desc, cCA, eidA,
                                                  ea, emb, dpw, dpb, out, N,
                                                  blocks * 4);
    } else {
        edge_kernel<<<(E + 255) / 256, 256, 0, stream>>>(z, ei, ew, ea, emb,
                                                         dpw, dpb, out, E);
    }

    combine_mfma<<<(N + 63) / 64, 256, 0, stream>>>(nf, cw, cb, out, N);
}

// Round 9
// 393.089 us; speedup vs baseline: 1.7691x; 1.1502x over previous
//
#include <hip/hip_runtime.h>

#define HIDDEN 128
#define NRBF 50
#define CUTOFF_F 5.0f
#define PI_OVER_CUTOFF 0.6283185307179586f
#define SLOT_U32 28      // 112B packed A-row per live edge
#define EPB 512          // edges per block in gather (4 waves x 128)
#define B_PITCH 35
#define W_PITCH 66

typedef _Float16 half8_t __attribute__((ext_vector_type(8)));
using f32x4_t  = __attribute__((ext_vector_type(4))) float;
using short8_t = __attribute__((ext_vector_type(8))) short;
typedef __attribute__((ext_vector_type(2))) _Float16 hf2;

static __device__ __forceinline__ unsigned int pkh(float a, float b) {
    return __builtin_bit_cast(unsigned int, __builtin_amdgcn_cvt_pkrtz(a, b));
}
static __device__ __forceinline__ float cvlo(unsigned int u) {
    return (float)__builtin_bit_cast(hf2, u)[0];
}
static __device__ __forceinline__ float cvhi(unsigned int u) {
    return (float)__builtin_bit_cast(hf2, u)[1];
}
static __device__ __forceinline__ unsigned int pk_bf16(float a, float b) {
    unsigned int ua = __float_as_uint(a), ub = __float_as_uint(b);
    ua = (ua + 0x7FFFu + ((ua >> 16) & 1u)) >> 16;
    ub = (ub + 0x7FFFu + ((ub >> 16) & 1u)) >> 16;
    return ua | (ub << 16);
}

// ======================= CSR build =======================

__global__ __launch_bounds__(256) void hist_kernel(
    const int* __restrict__ ei, const float* __restrict__ ew,
    int* __restrict__ cnt, int E)
{
    int e = blockIdx.x * 256 + threadIdx.x;
    if (e >= E) return;
    float r = ew[e];
    if (r < CUTOFF_F) atomicAdd(&cnt[ei[e]], 1);
}

__global__ __launch_bounds__(256) void scan1_kernel(
    const int* __restrict__ cnt, int* __restrict__ rowptr,
    int* __restrict__ bsum, int N)
{
    __shared__ int sh[256];
    int t = threadIdx.x, b = blockIdx.x;
    int base = b * 1024 + t * 4;
    int v[4];
#pragma unroll
    for (int j = 0; j < 4; ++j) v[j] = (base + j < N) ? cnt[base + j] : 0;
    int s = v[0] + v[1] + v[2] + v[3];
    sh[t] = s;
    __syncthreads();
    for (int off = 1; off < 256; off <<= 1) {
        int x = (t >= off) ? sh[t - off] : 0;
        __syncthreads();
        sh[t] += x;
        __syncthreads();
    }
    int run = sh[t] - s;
#pragma unroll
    for (int j = 0; j < 4; ++j) {
        if (base + j < N) rowptr[base + j] = run;
        run += v[j];
    }
    if (t == 255) bsum[b] = sh[255];
}

__global__ __launch_bounds__(256) void scan2_kernel(
    int* __restrict__ bsum, int* __restrict__ rowptr, int nb, int N)
{
    __shared__ int sh[256];
    int t = threadIdx.x;
    int v = (t < nb) ? bsum[t] : 0;
    sh[t] = v;
    __syncthreads();
    for (int off = 1; off < 256; off <<= 1) {
        int x = (t >= off) ? sh[t - off] : 0;
        __syncthreads();
        sh[t] += x;
        __syncthreads();
    }
    if (t < nb) bsum[t] = sh[t] - v;
    if (t == 255) rowptr[N] = sh[255];
}

__global__ __launch_bounds__(256) void scan3_kernel(
    int* __restrict__ rowptr, int* __restrict__ woff,
    const int* __restrict__ bsum, int N)
{
    int t = threadIdx.x, b = blockIdx.x;
    int base = b * 1024 + t * 4;
    int off = bsum[b];
#pragma unroll
    for (int j = 0; j < 4; ++j) {
        int i = base + j;
        if (i < N) {
            int r = rowptr[i] + off;
            rowptr[i] = r;
            woff[i] = r;
        }
    }
}

// zero the pad region [M, M+512) of desc and slots
__global__ __launch_bounds__(256) void pad_kernel(
    const int* __restrict__ rowptr, int N,
    int* __restrict__ desc, unsigned int* __restrict__ slots)
{
    int M = rowptr[N];
    int t = blockIdx.x * 256 + threadIdx.x;
    for (int i = t; i < 512; i += 256 * gridDim.x) desc[M + i] = 0;
    for (int i = t; i < 512 * SLOT_U32; i += 256 * gridDim.x)
        slots[(size_t)M * SLOT_U32 + i] = 0u;
}

// pack emb as f16 pairs (h, h+64): embp[t][j] = pkh(emb[t][j], emb[t][j+64])
__global__ __launch_bounds__(256) void pack_emb(
    const float* __restrict__ emb, unsigned int* __restrict__ embp, int NT)
{
    int i = blockIdx.x * 256 + threadIdx.x;
    if (i >= NT * 64) return;
    int t = i >> 6, j = i & 63;
    embp[i] = pkh(emb[t * HIDDEN + j], emb[t * HIDDEN + j + 64]);
}

// tier-1 scatter: CSR-reorder + pre-pack A-row (C*ea | C | 0) as f16, 112B
__global__ __launch_bounds__(256) void scatter_pack(
    const int* __restrict__ z, const int* __restrict__ ei,
    const float* __restrict__ ew, const float* __restrict__ ea,
    int* __restrict__ woff, int* __restrict__ desc,
    unsigned int* __restrict__ slots, int E)
{
    int e = blockIdx.x * 256 + threadIdx.x;
    if (e >= E) return;
    float r = ew[e];
    if (!(r < CUTOFF_F)) return;
    float C = 0.5f * (cosf(r * PI_OVER_CUTOFF) + 1.0f);
    int src = ei[e];
    int dst = ei[E + e];
    int zt  = z[dst];
    int p = atomicAdd(&woff[src], 1);
    desc[p] = src | (zt << 20);

    unsigned int buf[SLOT_U32];
    const float2* rp = (const float2*)(ea + (size_t)e * NRBF);
#pragma unroll
    for (int q = 0; q < 25; ++q) {
        float2 v = rp[q];
        buf[q] = pkh(C * v.x, C * v.y);
    }
    buf[25] = pkh(C, 0.f);
    buf[26] = 0u; buf[27] = 0u;
    uint4* sp = (uint4*)(slots + (size_t)p * SLOT_U32);
#pragma unroll
    for (int q = 0; q < 7; ++q) sp[q] = ((const uint4*)buf)[q];
}

// tier-2 scatter: descriptors only
__global__ __launch_bounds__(256) void scatter_simple(
    const int* __restrict__ z, const int* __restrict__ ei,
    const float* __restrict__ ew, int* __restrict__ woff,
    int* __restrict__ desc, float* __restrict__ cCA, int* __restrict__ eidA,
    int E)
{
    int e = blockIdx.x * 256 + threadIdx.x;
    if (e >= E) return;
    float r = ew[e];
    if (!(r < CUTOFF_F)) return;
    float C = 0.5f * (cosf(r * PI_OVER_CUTOFF) + 1.0f);
    int src = ei[e];
    int dst = ei[E + e];
    int zt  = z[dst];
    int p = atomicAdd(&woff[src], 1);
    desc[p] = src | (zt << 20);
    cCA[p]  = C;
    eidA[p] = e;
}

// ======================= tier-1 gather: streaming MFMA, low-pressure =======================
// B in LDS (re-read per tile); W transposed through per-wave LDS as f16 pairs
// (lane owns h = lane and lane+64); emb pre-packed; descs scalarized.
__global__ __launch_bounds__(256) void gather_mfma(
    const int* __restrict__ rowptr, const int* __restrict__ desc,
    const unsigned int* __restrict__ slots, const unsigned int* __restrict__ embp,
    const float* __restrict__ dpw, const float* __restrict__ dpb,
    float* __restrict__ agg, int N)
{
    __shared__ unsigned int Blds[128 * B_PITCH];        // 17.9KB
    __shared__ unsigned int Wlds[4][16 * W_PITCH];      // 16.9KB
    int M = rowptr[N];

    // bijective XCD-chunk swizzle
    int nwg = gridDim.x, orig = blockIdx.x;
    int q = nwg >> 3, r8 = nwg & 7, xcd = orig & 7, sub = orig >> 3;
    int lb = (xcd < r8) ? xcd * (q + 1) + sub
                        : r8 * (q + 1) + (xcd - r8) * q + sub;
    int gbase = lb * EPB;
    if (gbase >= M) return;

    int tid  = threadIdx.x;
    int w    = tid >> 6;
    int lane = tid & 63;
    int c    = lane & 15;
    int g    = lane >> 4;

    // stage B (f16 pairs, pitch 35)
    for (int idx = tid; idx < 128 * 32; idx += 256) {
        int h = idx >> 5, p = idx & 31;
        unsigned int u = 0u;
        if (p < 25) {
            float2 v = *(const float2*)(dpw + h * NRBF + 2 * p);
            u = pkh(v.x, v.y);
        } else if (p == 25) {
            u = pkh(dpb[h], 0.f);
        }
        Blds[h * B_PITCH + p] = u;
    }
    __syncthreads();

    unsigned int* Ww = Wlds[w];
    int wbeg = gbase + w * 128;
    if (wbeg >= M) return;

    bool runc;
    if (wbeg == 0) runc = true;
    else runc = ((desc[wbeg - 1] & 0xFFFFF) != (desc[wbeg] & 0xFFFFF));

    const int4* dp = (const int4*)(desc + wbeg);

    // prefetch tile 0
    const uint4* sp0 = (const uint4*)(slots + (size_t)(wbeg + c) * SLOT_U32);
    uint4 a0c = sp0[g];
    uint4 a1c = (g < 3) ? sp0[4 + g] : make_uint4(0u, 0u, 0u, 0u);
    int4 d0 = dp[0], d1 = dp[1], d2 = dp[2], d3 = dp[3];

    int   cur = -1;
    float r0 = 0.f, r1 = 0.f;

    for (int t = 0; t < 8; ++t) {
        int eb = wbeg + t * 16;
        uint4 A0u = a0c, A1u = a1c;
        // scalarize descriptors
        int s_[16];
        s_[0]=__builtin_amdgcn_readfirstlane(d0.x);  s_[1]=__builtin_amdgcn_readfirstlane(d0.y);
        s_[2]=__builtin_amdgcn_readfirstlane(d0.z);  s_[3]=__builtin_amdgcn_readfirstlane(d0.w);
        s_[4]=__builtin_amdgcn_readfirstlane(d1.x);  s_[5]=__builtin_amdgcn_readfirstlane(d1.y);
        s_[6]=__builtin_amdgcn_readfirstlane(d1.z);  s_[7]=__builtin_amdgcn_readfirstlane(d1.w);
        s_[8]=__builtin_amdgcn_readfirstlane(d2.x);  s_[9]=__builtin_amdgcn_readfirstlane(d2.y);
        s_[10]=__builtin_amdgcn_readfirstlane(d2.z); s_[11]=__builtin_amdgcn_readfirstlane(d2.w);
        s_[12]=__builtin_amdgcn_readfirstlane(d3.x); s_[13]=__builtin_amdgcn_readfirstlane(d3.y);
        s_[14]=__builtin_amdgcn_readfirstlane(d3.z); s_[15]=__builtin_amdgcn_readfirstlane(d3.w);

        // prefetch next tile
        if (t < 7) {
            const uint4* spn = (const uint4*)(slots + (size_t)(eb + 16 + c) * SLOT_U32);
            a0c = spn[g];
            a1c = (g < 3) ? spn[4 + g] : make_uint4(0u, 0u, 0u, 0u);
            d0 = dp[t * 4 + 4]; d1 = dp[t * 4 + 5];
            d2 = dp[t * 4 + 6]; d3 = dp[t * 4 + 7];
        }

        // packed emb loads (one b32 per edge, coalesced across lanes)
        unsigned int evp[16];
#pragma unroll
        for (int e2 = 0; e2 < 16; ++e2)
            evp[e2] = embp[(((unsigned int)s_[e2]) >> 20) * 64 + lane];

        // MFMA with B fragments from LDS
        half8_t A0 = __builtin_bit_cast(half8_t, A0u);
        half8_t A1 = __builtin_bit_cast(half8_t, A1u);
        f32x4_t acc[8];
#pragma unroll
        for (int nt = 0; nt < 8; ++nt) {
            uint4 b0 = *(const uint4*)&Blds[(nt * 16 + c) * B_PITCH + g * 4];
            uint4 b1 = *(const uint4*)&Blds[(nt * 16 + c) * B_PITCH + 16 + g * 4];
            f32x4_t a = (f32x4_t){0.f, 0.f, 0.f, 0.f};
            a = __builtin_amdgcn_mfma_f32_16x16x32_f16(A0, __builtin_bit_cast(half8_t, b0), a, 0, 0, 0);
            a = __builtin_amdgcn_mfma_f32_16x16x32_f16(A1, __builtin_bit_cast(half8_t, b1), a, 0, 0, 0);
            acc[nt] = a;
        }

        // W transpose to LDS as f16 pairs: word = (h=m*16+c, h+64)
#pragma unroll
        for (int m = 0; m < 4; ++m)
#pragma unroll
            for (int r = 0; r < 4; ++r)
                Ww[(g * 4 + r) * W_PITCH + m * 16 + c] = pkh(acc[m][r], acc[m + 4][r]);

        // batch-read W for the 16 edges
        unsigned int wv[16];
#pragma unroll
        for (int e2 = 0; e2 < 16; ++e2)
            wv[e2] = Ww[e2 * W_PITCH + lane];

        // register run-merge (pure VALU, scalar branches)
#pragma unroll
        for (int e2 = 0; e2 < 16; ++e2) {
            int src = s_[e2] & 0xFFFFF;
            if (src != cur) {
                if (cur >= 0) {
                    float* dst = agg + (size_t)cur * HIDDEN + lane;
                    if (runc) {
                        dst[0]  = r0;
                        dst[64] = r1;
                    } else {
                        unsafeAtomicAdd(dst,      r0);
                        unsafeAtomicAdd(dst + 64, r1);
                    }
                    runc = true;
                }
                cur = src; r0 = 0.f; r1 = 0.f;
            }
            r0 = fmaf(cvlo(wv[e2]), cvlo(evp[e2]), r0);
            r1 = fmaf(cvhi(wv[e2]), cvhi(evp[e2]), r1);
        }
    }
    if (cur >= 0) {
        int nxt = desc[wbeg + 128] & 0xFFFFF;
        float* dst = agg + (size_t)cur * HIDDEN + lane;
        if (runc && nxt != cur) {
            dst[0]  = r0;
            dst[64] = r1;
        } else {
            unsafeAtomicAdd(dst,      r0);
            unsafeAtomicAdd(dst + 64, r1);
        }
    }
}

// ======================= tier-2 gather: VALU streaming =======================
__global__ __launch_bounds__(256) void gather_stream(
    const int* __restrict__ rowptr, const int* __restrict__ desc,
    const float* __restrict__ cC, const int* __restrict__ eidA,
    const float* __restrict__ ea, const float* __restrict__ emb,
    const float* __restrict__ dpw, const float* __restrict__ dpb,
    float* __restrict__ agg, int N, int nwaves)
{
    __shared__ unsigned int sh_ea[4][4][32];
    int lane  = threadIdx.x & 63;
    int wslot = threadIdx.x >> 6;
    int wid = __builtin_amdgcn_readfirstlane((int)((blockIdx.x * blockDim.x + threadIdx.x) >> 6));

    hf2 whA[25], whB[25];
    {
        const float* wr0 = dpw + (size_t)(2 * lane) * NRBF;
        const float* wr1 = wr0 + NRBF;
#pragma unroll
        for (int q = 0; q < 25; ++q) {
            float2 x = *(const float2*)(wr0 + 2 * q);
            float2 y = *(const float2*)(wr1 + 2 * q);
            whA[q] = __builtin_bit_cast(hf2, pkh(x.x, x.y));
            whB[q] = __builtin_bit_cast(hf2, pkh(y.x, y.y));
        }
    }
    float2 db = *(const float2*)(dpb + 2 * lane);

    int M  = rowptr[N];
    int CH = (M + nwaves - 1) / nwaves;
    int c0 = min(wid * CH, M);
    int c1 = min(c0 + CH, M);

    int   cur = -1, run_start = c0;
    float a0 = 0.f, a1 = 0.f;

    for (int i = c0; i < c1; i += 4) {
        int sv[4]; float cf[4]; int ed[4]; float2 ev[4]; float2 eaf[4];
#pragma unroll
        for (int j = 0; j < 4; ++j)
            if (i + j < c1) { sv[j] = desc[i + j]; cf[j] = cC[i + j]; ed[j] = eidA[i + j]; }
#pragma unroll
        for (int j = 0; j < 4; ++j)
            if (i + j < c1) ev[j] = *(const float2*)(emb + (size_t)((unsigned int)sv[j] >> 20) * HIDDEN + 2 * lane);
#pragma unroll
        for (int j = 0; j < 4; ++j)
            if (i + j < c1 && lane < 25) eaf[j] = *(const float2*)(ea + (size_t)ed[j] * NRBF + 2 * lane);
#pragma unroll
        for (int j = 0; j < 4; ++j)
            if (i + j < c1 && lane < 28) {
                unsigned int u = 0u;
                if (lane < 25) u = pkh(eaf[j].x, eaf[j].y);
                sh_ea[wslot][j][lane] = u;
            }
#pragma unroll
        for (int j = 0; j < 4; ++j) {
            if (i + j >= c1) break;
            int src = sv[j] & 0xFFFFF;
            if (src != cur) {
                if (cur >= 0) {
                    int rp0 = rowptr[cur], rp1 = rowptr[cur + 1];
                    float* dst = agg + (size_t)cur * HIDDEN + 2 * lane;
                    if (run_start == rp0 && (i + j) == rp1) {
                        *(float2*)dst = make_float2(a0, a1);
                    } else {
                        unsafeAtomicAdd(dst, a0);
                        unsafeAtomicAdd(dst + 1, a1);
                    }
                }
                cur = src; run_start = i + j; a0 = 0.f; a1 = 0.f;
            }
            float s0 = 0.f, s1 = 0.f;
#pragma unroll
            for (int qq = 0; qq < 6; ++qq) {
                uint4 u = *(const uint4*)&sh_ea[wslot][j][qq * 4];
#pragma unroll
                for (int t = 0; t < 4; ++t) {
                    unsigned int ww = (t == 0) ? u.x : (t == 1) ? u.y : (t == 2) ? u.z : u.w;
                    hf2 e2 = __builtin_bit_cast(hf2, ww);
                    s0 = fmaf((float)e2[0], (float)whA[qq*4+t][0], fmaf((float)e2[1], (float)whA[qq*4+t][1], s0));
                    s1 = fmaf((float)e2[0], (float)whB[qq*4+t][0], fmaf((float)e2[1], (float)whB[qq*4+t][1], s1));
                }
            }
            {
                hf2 e2 = __builtin_bit_cast(hf2, sh_ea[wslot][j][24]);
                s0 = fmaf((float)e2[0], (float)whA[24][0], fmaf((float)e2[1], (float)whA[24][1], s0));
                s1 = fmaf((float)e2[0], (float)whB[24][0], fmaf((float)e2[1], (float)whB[24][1], s1));
            }
            float W0 = (s0 + db.x) * cf[j];
            float W1 = (s1 + db.y) * cf[j];
            a0 = fmaf(W0, ev[j].x, a0);
            a1 = fmaf(W1, ev[j].y, a1);
        }
    }
    if (cur >= 0) {
        int rp0 = rowptr[cur], rp1 = rowptr[cur + 1];
        float* dst = agg + (size_t)cur * HIDDEN + 2 * lane;
        if (run_start == rp0 && c1 == rp1) {
            *(float2*)dst = make_float2(a0, a1);
        } else {
            unsafeAtomicAdd(dst, a0);
            unsafeAtomicAdd(dst + 1, a1);
        }
    }
}

// ======================= tier-3 fallback =======================
__global__ __launch_bounds__(256) void edge_kernel(
    const int* __restrict__ z, const int* __restrict__ ei,
    const float* __restrict__ ew, const float* __restrict__ ea,
    const float* __restrict__ emb, const float* __restrict__ dpw,
    const float* __restrict__ dpb, float* __restrict__ agg, int E)
{
    int e = blockIdx.x * 256 + threadIdx.x;
    if (e >= E) return;
    float r = ew[e];
    if (!(r < CUTOFF_F)) return;
    float C = 0.5f * (cosf(r * PI_OVER_CUTOFF) + 1.0f);
    int src = ei[e];
    int dst = ei[E + e];
    int zt  = z[dst];
    float av[NRBF];
#pragma unroll
    for (int k = 0; k < NRBF; ++k) av[k] = ea[(size_t)e * NRBF + k];
    const float* er = emb + (size_t)zt * HIDDEN;
    float*       ar = agg + (size_t)src * HIDDEN;
#pragma unroll 2
    for (int h = 0; h < HIDDEN; ++h) {
        const float* wrow = dpw + h * NRBF;
        float s0 = 0.f, s1 = 0.f;
#pragma unroll
        for (int k = 0; k < NRBF; k += 2) {
            s0 = fmaf(av[k],     wrow[k],     s0);
            s1 = fmaf(av[k + 1], wrow[k + 1], s1);
        }
        float w2 = (dpb[h] + s0 + s1) * C;
        unsafeAtomicAdd(&ar[h], w2 * er[h]);
    }
}

// ======================= Combine: bf16 MFMA GEMM =======================
__global__ __launch_bounds__(256) void combine_mfma(
    const float* __restrict__ nf, const float* __restrict__ cw,
    const float* __restrict__ cbias, float* out, int N)
{
    __shared__ unsigned int As_u[64 * 20];
    __shared__ unsigned int Bs_u[128 * 20];
    int tid  = threadIdx.x;
    int w    = tid >> 6;
    int lane = tid & 63;
    int c    = lane & 15;
    int g    = lane >> 4;
    int row0 = blockIdx.x * 64;

    f32x4_t acc[8];
#pragma unroll
    for (int q = 0; q < 8; ++q) acc[q] = (f32x4_t){0.f, 0.f, 0.f, 0.f};

    for (int ks = 0; ks < 8; ++ks) {
        const float* src = (ks < 4) ? nf : out;
        int kb = (ks & 3) * 32;
        {
            int r = tid >> 2, kq = tid & 3;
            int row = row0 + r;
            float4 v0 = make_float4(0.f, 0.f, 0.f, 0.f), v1 = v0;
            if (row < N) {
                const float4* p = (const float4*)(src + (size_t)row * HIDDEN + kb + kq * 8);
                v0 = p[0]; v1 = p[1];
            }
            *(uint4*)&As_u[r * 20 + kq * 4] =
                make_uint4(pk_bf16(v0.x, v0.y), pk_bf16(v0.z, v0.w),
                           pk_bf16(v1.x, v1.y), pk_bf16(v1.z, v1.w));
        }
        {
            int j = tid >> 1, hf = tid & 1;
            const float4* p = (const float4*)(cw + (size_t)j * 256 + ks * 32 + hf * 16);
            float4 b0 = p[0], b1 = p[1], b2 = p[2], b3 = p[3];
            *(uint4*)&Bs_u[j * 20 + hf * 8] =
                make_uint4(pk_bf16(b0.x, b0.y), pk_bf16(b0.z, b0.w),
                           pk_bf16(b1.x, b1.y), pk_bf16(b1.z, b1.w));
            *(uint4*)&Bs_u[j * 20 + hf * 8 + 4] =
                make_uint4(pk_bf16(b2.x, b2.y), pk_bf16(b2.z, b2.w),
                           pk_bf16(b3.x, b3.y), pk_bf16(b3.z, b3.w));
        }
        __syncthreads();
        uint4 au = *(const uint4*)&As_u[(w * 16 + c) * 20 + g * 4];
        short8_t af = __builtin_bit_cast(short8_t, au);
#pragma unroll
        for (int cbk = 0; cbk < 8; ++cbk) {
            uint4 bu = *(const uint4*)&Bs_u[(cbk * 16 + c) * 20 + g * 4];
            short8_t bf = __builtin_bit_cast(short8_t, bu);
            acc[cbk] = __builtin_amdgcn_mfma_f32_16x16x32_bf16(af, bf, acc[cbk], 0, 0, 0);
        }
        __syncthreads();
    }
#pragma unroll
    for (int cbk = 0; cbk < 8; ++cbk) {
        float bias = cbias[cbk * 16 + c];
#pragma unroll
        for (int r = 0; r < 4; ++r) {
            int row = row0 + w * 16 + g * 4 + r;
            if (row < N) out[(size_t)row * HIDDEN + cbk * 16 + c] = acc[cbk][r] + bias;
        }
    }
}

// ======================= launch =======================

extern "C" void kernel_launch(void* const* d_in, const int* in_sizes, int n_in,
                              void* d_out, int out_size, void* d_ws, size_t ws_size,
                              hipStream_t stream)
{
    const int*   z   = (const int*)  d_in[0];
    const float* nf  = (const float*)d_in[1];
    const int*   ei  = (const int*)  d_in[2];
    const float* ew  = (const float*)d_in[3];
    const float* ea  = (const float*)d_in[4];
    const float* emb = (const float*)d_in[5];
    const float* dpw = (const float*)d_in[6];
    const float* dpb = (const float*)d_in[7];
    const float* cw  = (const float*)d_in[8];
    const float* cb  = (const float*)d_in[9];
    float* out = (float*)d_out;

    int N = in_sizes[0];
    int E = in_sizes[3];
    int NT = in_sizes[5] / HIDDEN;   // emb rows (95)

    size_t hdr  = ((size_t)2 * N + 1 + 1024 + 3) & ~(size_t)3;             // u32s
    size_t Epad = (size_t)E + 512;
    size_t need1 = (hdr + Epad + Epad * SLOT_U32 + (size_t)NT * 64 + 16) * 4;
    size_t need2 = (hdr + (size_t)3 * E) * 4;

    (void)hipMemsetAsync(out, 0, (size_t)N * HIDDEN * sizeof(float), stream);

    int nb1 = (N + 1023) / 1024;

    if (ws_size >= need1) {
        int* rowptr = (int*)d_ws;
        int* woff   = rowptr + (N + 1);
        int* bsum   = woff + N;
        int* desc   = (int*)d_ws + hdr;
        unsigned int* slots = (unsigned int*)(desc + Epad);
        slots = (unsigned int*)(((size_t)slots + 15) & ~(size_t)15);
        unsigned int* embp = slots + Epad * SLOT_U32;

        (void)hipMemsetAsync(woff, 0, (size_t)N * 4, stream);
        hist_kernel<<<(E + 255) / 256, 256, 0, stream>>>(ei, ew, woff, E);
        scan1_kernel<<<nb1, 256, 0, stream>>>(woff, rowptr, bsum, N);
        scan2_kernel<<<1, 256, 0, stream>>>(bsum, rowptr, nb1, N);
        scan3_kernel<<<nb1, 256, 0, stream>>>(rowptr, woff, bsum, N);
        pack_emb<<<(NT * 64 + 255) / 256, 256, 0, stream>>>(emb, embp, NT);
        scatter_pack<<<(E + 255) / 256, 256, 0, stream>>>(z, ei, ew, ea, woff,
                                                          desc, slots, E);
        pad_kernel<<<8, 256, 0, stream>>>(rowptr, N, desc, slots);
        int nblk = (E + EPB - 1) / EPB;
        gather_mfma<<<nblk, 256, 0, stream>>>(rowptr, desc, slots, embp,
                                              dpw, dpb, out, N);
    } else if (ws_size >= need2) {
        int* rowptr = (int*)d_ws;
        int* woff   = rowptr + (N + 1);
        int* bsum   = woff + N;
        int* desc   = (int*)d_ws + hdr;
        float* cCA  = (float*)(desc + E);
        int* eidA   = (int*)(cCA + E);

        (void)hipMemsetAsync(woff, 0, (size_t)N * 4, stream);
        hist_kernel<<<(E + 255) / 256, 256, 0, stream>>>(ei, ew, woff, E);
        scan1_kernel<<<nb1, 256, 0, stream>>>(woff, rowptr, bsum, N);
        scan2_kernel<<<1, 256, 0, stream>>>(bsum, rowptr, nb1, N);
        scan3_kernel<<<nb1, 256, 0, stream>>>(rowptr, woff, bsum, N);
        scatter_simple<<<(E + 255) / 256, 256, 0, stream>>>(z, ei, ew, woff,
                                                            desc, cCA, eidA, E);
        const int blocks = 2048;
        gather_stream<<<blocks, 256, 0, stream>>>(rowptr, desc, cCA, eidA,
                                                  ea, emb, dpw, dpb, out, N,
                                                  blocks * 4);
    } else {
        edge_kernel<<<(E + 255) / 256, 256, 0, stream>>>(z, ei, ew, ea, emb,
                                                         dpw, dpb, out, E);
    }

    combine_mfma<<<(N + 63) / 64, 256, 0, stream>>>(nf, cw, cb, out, N);
}

// Round 10
// 382.893 us; speedup vs baseline: 1.8163x; 1.0266x over previous
//
#include <hip/hip_runtime.h>

#define HIDDEN 128
#define NRBF 50
#define CUTOFF_F 5.0f
#define PI_OVER_CUTOFF 0.6283185307179586f
#define EPB 512          // edges per block in gather (4 waves x 128)
#define B_PITCH 35
#define W_PITCH 66
#define A_PITCH 68

typedef _Float16 half8_t __attribute__((ext_vector_type(8)));
using f32x4_t  = __attribute__((ext_vector_type(4))) float;
using short8_t = __attribute__((ext_vector_type(8))) short;
typedef __attribute__((ext_vector_type(2))) _Float16 hf2;

static __device__ __forceinline__ unsigned int pkh(float a, float b) {
    return __builtin_bit_cast(unsigned int, __builtin_amdgcn_cvt_pkrtz(a, b));
}
static __device__ __forceinline__ float cvlo(unsigned int u) {
    return (float)__builtin_bit_cast(hf2, u)[0];
}
static __device__ __forceinline__ float cvhi(unsigned int u) {
    return (float)__builtin_bit_cast(hf2, u)[1];
}
static __device__ __forceinline__ unsigned int pk_bf16(float a, float b) {
    unsigned int ua = __float_as_uint(a), ub = __float_as_uint(b);
    ua = (ua + 0x7FFFu + ((ua >> 16) & 1u)) >> 16;
    ub = (ub + 0x7FFFu + ((ub >> 16) & 1u)) >> 16;
    return ua | (ub << 16);
}
static __device__ __forceinline__ void loadd16(const int4* p, int t, int* s) {
    int4 q0 = p[t * 4], q1 = p[t * 4 + 1], q2 = p[t * 4 + 2], q3 = p[t * 4 + 3];
    s[0]  = __builtin_amdgcn_readfirstlane(q0.x);
    s[1]  = __builtin_amdgcn_readfirstlane(q0.y);
    s[2]  = __builtin_amdgcn_readfirstlane(q0.z);
    s[3]  = __builtin_amdgcn_readfirstlane(q0.w);
    s[4]  = __builtin_amdgcn_readfirstlane(q1.x);
    s[5]  = __builtin_amdgcn_readfirstlane(q1.y);
    s[6]  = __builtin_amdgcn_readfirstlane(q1.z);
    s[7]  = __builtin_amdgcn_readfirstlane(q1.w);
    s[8]  = __builtin_amdgcn_readfirstlane(q2.x);
    s[9]  = __builtin_amdgcn_readfirstlane(q2.y);
    s[10] = __builtin_amdgcn_readfirstlane(q2.z);
    s[11] = __builtin_amdgcn_readfirstlane(q2.w);
    s[12] = __builtin_amdgcn_readfirstlane(q3.x);
    s[13] = __builtin_amdgcn_readfirstlane(q3.y);
    s[14] = __builtin_amdgcn_readfirstlane(q3.z);
    s[15] = __builtin_amdgcn_readfirstlane(q3.w);
}

// ======================= CSR build =======================

__global__ __launch_bounds__(256) void hist_kernel(
    const int* __restrict__ ei, const float* __restrict__ ew,
    int* __restrict__ cnt, int E)
{
    int e = blockIdx.x * 256 + threadIdx.x;
    if (e >= E) return;
    float r = ew[e];
    if (r < CUTOFF_F) atomicAdd(&cnt[ei[e]], 1);
}

__global__ __launch_bounds__(256) void scan1_kernel(
    const int* __restrict__ cnt, int* __restrict__ rowptr,
    int* __restrict__ bsum, int N)
{
    __shared__ int sh[256];
    int t = threadIdx.x, b = blockIdx.x;
    int base = b * 1024 + t * 4;
    int v[4];
#pragma unroll
    for (int j = 0; j < 4; ++j) v[j] = (base + j < N) ? cnt[base + j] : 0;
    int s = v[0] + v[1] + v[2] + v[3];
    sh[t] = s;
    __syncthreads();
    for (int off = 1; off < 256; off <<= 1) {
        int x = (t >= off) ? sh[t - off] : 0;
        __syncthreads();
        sh[t] += x;
        __syncthreads();
    }
    int run = sh[t] - s;
#pragma unroll
    for (int j = 0; j < 4; ++j) {
        if (base + j < N) rowptr[base + j] = run;
        run += v[j];
    }
    if (t == 255) bsum[b] = sh[255];
}

__global__ __launch_bounds__(256) void scan2_kernel(
    int* __restrict__ bsum, int* __restrict__ rowptr, int nb, int N)
{
    __shared__ int sh[256];
    int t = threadIdx.x;
    int v = (t < nb) ? bsum[t] : 0;
    sh[t] = v;
    __syncthreads();
    for (int off = 1; off < 256; off <<= 1) {
        int x = (t >= off) ? sh[t - off] : 0;
        __syncthreads();
        sh[t] += x;
        __syncthreads();
    }
    if (t < nb) bsum[t] = sh[t] - v;
    if (t == 255) rowptr[N] = sh[255];
}

__global__ __launch_bounds__(256) void scan3_kernel(
    int* __restrict__ rowptr, int* __restrict__ woff,
    const int* __restrict__ bsum, int N)
{
    int t = threadIdx.x, b = blockIdx.x;
    int base = b * 1024 + t * 4;
    int off = bsum[b];
#pragma unroll
    for (int j = 0; j < 4; ++j) {
        int i = base + j;
        if (i < N) {
            int r = rowptr[i] + off;
            rowptr[i] = r;
            woff[i] = r;
        }
    }
}

// zero pad region [M, M+512) of desc/eid/C (C=0 => zero contribution)
__global__ __launch_bounds__(256) void pad_kernel(
    const int* __restrict__ rowptr, int N,
    int* __restrict__ desc, int* __restrict__ eidA, float* __restrict__ CA)
{
    int M = rowptr[N];
    int t = blockIdx.x * 256 + threadIdx.x;
    if (t < 512) { desc[M + t] = 0; eidA[M + t] = 0; CA[M + t] = 0.f; }
}

// pack emb as f16 pairs (h, h+64)
__global__ __launch_bounds__(256) void pack_emb(
    const float* __restrict__ emb, unsigned int* __restrict__ embp, int NT)
{
    int i = blockIdx.x * 256 + threadIdx.x;
    if (i >= NT * 64) return;
    int t = i >> 6, j = i & 63;
    embp[i] = pkh(emb[t * HIDDEN + j], emb[t * HIDDEN + j + 64]);
}

// tier-1 scatter: slim descriptors only (12B/edge, L2-absorbed)
__global__ __launch_bounds__(256) void scatter_slim(
    const int* __restrict__ z, const int* __restrict__ ei,
    const float* __restrict__ ew, int* __restrict__ woff,
    int* __restrict__ desc, int* __restrict__ eidA, float* __restrict__ CA,
    int E)
{
    int e = blockIdx.x * 256 + threadIdx.x;
    if (e >= E) return;
    float r = ew[e];
    if (!(r < CUTOFF_F)) return;
    float C = 0.5f * (cosf(r * PI_OVER_CUTOFF) + 1.0f);
    int src = ei[e];
    int dst = ei[E + e];
    int zt  = z[dst];
    int p = atomicAdd(&woff[src], 1);
    desc[p] = src | (zt << 20);
    eidA[p] = e;
    CA[p]   = C;
}

// ======================= tier-1 gather: direct-ea streaming MFMA =======================
// Per 16-edge tile: 16 wave-wide ea-row loads (eids scalarized), double-
// pipelined; LDS transpose [16][68] -> f16 A-fragments (xC in-register);
// MFMA vs B (LDS); W transposed through LDS; register run-merge.
__global__ __launch_bounds__(256) void gather_mfma(
    const int* __restrict__ rowptr, const int* __restrict__ desc,
    const int* __restrict__ eidA, const float* __restrict__ CA,
    const float* __restrict__ ea, const unsigned int* __restrict__ embp,
    const float* __restrict__ dpw, const float* __restrict__ dpb,
    float* __restrict__ agg, int N)
{
    __shared__ unsigned int Blds[128 * B_PITCH];     // 17.9KB
    __shared__ float        Ast[4][16 * A_PITCH];    // 17.4KB
    __shared__ unsigned int Wlds[4][16 * W_PITCH];   // 16.9KB
    int M = rowptr[N];

    // bijective XCD-chunk swizzle
    int nwg = gridDim.x, orig = blockIdx.x;
    int q = nwg >> 3, r8 = nwg & 7, xcd = orig & 7, sub = orig >> 3;
    int lb = (xcd < r8) ? xcd * (q + 1) + sub
                        : r8 * (q + 1) + (xcd - r8) * q + sub;
    int gbase = lb * EPB;
    if (gbase >= M) return;

    int tid  = threadIdx.x;
    int w    = tid >> 6;
    int lane = tid & 63;
    int c    = lane & 15;
    int g    = lane >> 4;
    int lidx = min(lane, 49);

    // stage B (f16 pairs, pitch 35)
    for (int idx = tid; idx < 128 * 32; idx += 256) {
        int h = idx >> 5, p = idx & 31;
        unsigned int u = 0u;
        if (p < 25) {
            float2 v = *(const float2*)(dpw + h * NRBF + 2 * p);
            u = pkh(v.x, v.y);
        } else if (p == 25) {
            u = pkh(dpb[h], 0.f);
        }
        Blds[h * B_PITCH + p] = u;
    }
    __syncthreads();

    float*        AstW = Ast[w];
    unsigned int* Ww   = Wlds[w];
    int wbeg = gbase + w * 128;
    if (wbeg >= M) return;

    bool runc;
    if (wbeg == 0) runc = true;
    else runc = ((desc[wbeg - 1] & 0xFFFFF) != (desc[wbeg] & 0xFFFFF));

    const int4* dp = (const int4*)(desc + wbeg);
    const int4* ep = (const int4*)(eidA + wbeg);

    int sd[16], se[16], sdN[16], seN[16];
    float vr[16], vrN[16];

    // prologue: tile 0 descriptors + ea loads, tile 1 descriptors
    loadd16(dp, 0, sd);
    loadd16(ep, 0, se);
    float vC = CA[wbeg + c];
#pragma unroll
    for (int j = 0; j < 16; ++j)
        vr[j] = ea[(size_t)(unsigned int)se[j] * NRBF + lidx];
    loadd16(dp, 1, sdN);
    loadd16(ep, 1, seN);
    float vCN = CA[wbeg + 16 + c];

    int   cur = -1;
    float r0 = 0.f, r1 = 0.f;

    for (int t = 0; t < 8; ++t) {
        // issue next tile's ea row loads (latency hidden under this tile)
        if (t < 7) {
#pragma unroll
            for (int j = 0; j < 16; ++j)
                vrN[j] = ea[(size_t)(unsigned int)seN[j] * NRBF + lidx];
        }
        // packed emb loads (one b32 per edge, L2-hot)
        unsigned int evp[16];
#pragma unroll
        for (int j = 0; j < 16; ++j)
            evp[j] = embp[(((unsigned int)sd[j]) >> 20) * 64 + lane];

        // stage A rows: lane l holds elem l of edge j
#pragma unroll
        for (int j = 0; j < 16; ++j)
            AstW[j * A_PITCH + lane] = vr[j];

        // build A fragments for edge c (xC, f16-packed)
        const float* ab = &AstW[c * A_PITCH];
        float4 f0 = *(const float4*)&ab[g * 8];
        float4 f1 = *(const float4*)&ab[g * 8 + 4];
        uint4 A0u = make_uint4(pkh(vC * f0.x, vC * f0.y), pkh(vC * f0.z, vC * f0.w),
                               pkh(vC * f1.x, vC * f1.y), pkh(vC * f1.z, vC * f1.w));
        uint4 A1u;
        if (g < 2) {
            float4 h0 = *(const float4*)&ab[32 + g * 8];
            float4 h1 = *(const float4*)&ab[36 + g * 8];
            A1u = make_uint4(pkh(vC * h0.x, vC * h0.y), pkh(vC * h0.z, vC * h0.w),
                             pkh(vC * h1.x, vC * h1.y), pkh(vC * h1.z, vC * h1.w));
        } else if (g == 2) {
            float2 hv = *(const float2*)&ab[48];
            A1u = make_uint4(pkh(vC * hv.x, vC * hv.y), pkh(vC, 0.f), 0u, 0u);
        } else {
            A1u = make_uint4(0u, 0u, 0u, 0u);
        }
        half8_t A0 = __builtin_bit_cast(half8_t, A0u);
        half8_t A1 = __builtin_bit_cast(half8_t, A1u);

        // MFMA vs B (from LDS)
        f32x4_t acc[8];
#pragma unroll
        for (int nt = 0; nt < 8; ++nt) {
            uint4 b0 = *(const uint4*)&Blds[(nt * 16 + c) * B_PITCH + g * 4];
            uint4 b1 = *(const uint4*)&Blds[(nt * 16 + c) * B_PITCH + 16 + g * 4];
            f32x4_t a = (f32x4_t){0.f, 0.f, 0.f, 0.f};
            a = __builtin_amdgcn_mfma_f32_16x16x32_f16(A0, __builtin_bit_cast(half8_t, b0), a, 0, 0, 0);
            a = __builtin_amdgcn_mfma_f32_16x16x32_f16(A1, __builtin_bit_cast(half8_t, b1), a, 0, 0, 0);
            acc[nt] = a;
        }

        // W transpose to LDS as f16 pairs (h = m*16+c, h+64)
#pragma unroll
        for (int m = 0; m < 4; ++m)
#pragma unroll
            for (int r = 0; r < 4; ++r)
                Ww[(g * 4 + r) * W_PITCH + m * 16 + c] = pkh(acc[m][r], acc[m + 4][r]);

        unsigned int wv[16];
#pragma unroll
        for (int e2 = 0; e2 < 16; ++e2)
            wv[e2] = Ww[e2 * W_PITCH + lane];

        // register run-merge
#pragma unroll
        for (int e2 = 0; e2 < 16; ++e2) {
            int src = sd[e2] & 0xFFFFF;
            if (src != cur) {
                if (cur >= 0) {
                    float* dst = agg + (size_t)cur * HIDDEN + lane;
                    if (runc) {
                        dst[0]  = r0;
                        dst[64] = r1;
                    } else {
                        unsafeAtomicAdd(dst,      r0);
                        unsafeAtomicAdd(dst + 64, r1);
                    }
                    runc = true;
                }
                cur = src; r0 = 0.f; r1 = 0.f;
            }
            r0 = fmaf(cvlo(wv[e2]), cvlo(evp[e2]), r0);
            r1 = fmaf(cvhi(wv[e2]), cvhi(evp[e2]), r1);
        }

        // rotate pipeline, prefetch t+2 descriptors
        if (t < 7) {
#pragma unroll
            for (int k = 0; k < 16; ++k) { sd[k] = sdN[k]; se[k] = seN[k]; vr[k] = vrN[k]; }
            vC = vCN;
            if (t < 6) {
                loadd16(dp, t + 2, sdN);
                loadd16(ep, t + 2, seN);
                vCN = CA[wbeg + (t + 2) * 16 + c];
            }
        }
    }
    // final flush
    if (cur >= 0) {
        int nxt = desc[wbeg + 128] & 0xFFFFF;
        float* dst = agg + (size_t)cur * HIDDEN + lane;
        if (runc && nxt != cur) {
            dst[0]  = r0;
            dst[64] = r1;
        } else {
            unsafeAtomicAdd(dst,      r0);
            unsafeAtomicAdd(dst + 64, r1);
        }
    }
}

// ======================= tier-2 gather: VALU streaming =======================
__global__ __launch_bounds__(256) void gather_stream(
    const int* __restrict__ rowptr, const int* __restrict__ desc,
    const float* __restrict__ cC, const int* __restrict__ eidA,
    const float* __restrict__ ea, const float* __restrict__ emb,
    const float* __restrict__ dpw, const float* __restrict__ dpb,
    float* __restrict__ agg, int N, int nwaves)
{
    __shared__ unsigned int sh_ea[4][4][32];
    int lane  = threadIdx.x & 63;
    int wslot = threadIdx.x >> 6;
    int wid = __builtin_amdgcn_readfirstlane((int)((blockIdx.x * blockDim.x + threadIdx.x) >> 6));

    hf2 whA[25], whB[25];
    {
        const float* wr0 = dpw + (size_t)(2 * lane) * NRBF;
        const float* wr1 = wr0 + NRBF;
#pragma unroll
        for (int q = 0; q < 25; ++q) {
            float2 x = *(const float2*)(wr0 + 2 * q);
            float2 y = *(const float2*)(wr1 + 2 * q);
            whA[q] = __builtin_bit_cast(hf2, pkh(x.x, x.y));
            whB[q] = __builtin_bit_cast(hf2, pkh(y.x, y.y));
        }
    }
    float2 db = *(const float2*)(dpb + 2 * lane);

    int M  = rowptr[N];
    int CH = (M + nwaves - 1) / nwaves;
    int c0 = min(wid * CH, M);
    int c1 = min(c0 + CH, M);

    int   cur = -1, run_start = c0;
    float a0 = 0.f, a1 = 0.f;

    for (int i = c0; i < c1; i += 4) {
        int sv[4]; float cf[4]; int ed[4]; float2 ev[4]; float2 eaf[4];
#pragma unroll
        for (int j = 0; j < 4; ++j)
            if (i + j < c1) { sv[j] = desc[i + j]; cf[j] = cC[i + j]; ed[j] = eidA[i + j]; }
#pragma unroll
        for (int j = 0; j < 4; ++j)
            if (i + j < c1) ev[j] = *(const float2*)(emb + (size_t)((unsigned int)sv[j] >> 20) * HIDDEN + 2 * lane);
#pragma unroll
        for (int j = 0; j < 4; ++j)
            if (i + j < c1 && lane < 25) eaf[j] = *(const float2*)(ea + (size_t)ed[j] * NRBF + 2 * lane);
#pragma unroll
        for (int j = 0; j < 4; ++j)
            if (i + j < c1 && lane < 28) {
                unsigned int u = 0u;
                if (lane < 25) u = pkh(eaf[j].x, eaf[j].y);
                sh_ea[wslot][j][lane] = u;
            }
#pragma unroll
        for (int j = 0; j < 4; ++j) {
            if (i + j >= c1) break;
            int src = sv[j] & 0xFFFFF;
            if (src != cur) {
                if (cur >= 0) {
                    int rp0 = rowptr[cur], rp1 = rowptr[cur + 1];
                    float* dst = agg + (size_t)cur * HIDDEN + 2 * lane;
                    if (run_start == rp0 && (i + j) == rp1) {
                        *(float2*)dst = make_float2(a0, a1);
                    } else {
                        unsafeAtomicAdd(dst, a0);
                        unsafeAtomicAdd(dst + 1, a1);
                    }
                }
                cur = src; run_start = i + j; a0 = 0.f; a1 = 0.f;
            }
            float s0 = 0.f, s1 = 0.f;
#pragma unroll
            for (int qq = 0; qq < 6; ++qq) {
                uint4 u = *(const uint4*)&sh_ea[wslot][j][qq * 4];
#pragma unroll
                for (int t = 0; t < 4; ++t) {
                    unsigned int ww = (t == 0) ? u.x : (t == 1) ? u.y : (t == 2) ? u.z : u.w;
                    hf2 e2 = __builtin_bit_cast(hf2, ww);
                    s0 = fmaf((float)e2[0], (float)whA[qq*4+t][0], fmaf((float)e2[1], (float)whA[qq*4+t][1], s0));
                    s1 = fmaf((float)e2[0], (float)whB[qq*4+t][0], fmaf((float)e2[1], (float)whB[qq*4+t][1], s1));
                }
            }
            {
                hf2 e2 = __builtin_bit_cast(hf2, sh_ea[wslot][j][24]);
                s0 = fmaf((float)e2[0], (float)whA[24][0], fmaf((float)e2[1], (float)whA[24][1], s0));
                s1 = fmaf((float)e2[0], (float)whB[24][0], fmaf((float)e2[1], (float)whB[24][1], s1));
            }
            float W0 = (s0 + db.x) * cf[j];
            float W1 = (s1 + db.y) * cf[j];
            a0 = fmaf(W0, ev[j].x, a0);
            a1 = fmaf(W1, ev[j].y, a1);
        }
    }
    if (cur >= 0) {
        int rp0 = rowptr[cur], rp1 = rowptr[cur + 1];
        float* dst = agg + (size_t)cur * HIDDEN + 2 * lane;
        if (run_start == rp0 && c1 == rp1) {
            *(float2*)dst = make_float2(a0, a1);
        } else {
            unsafeAtomicAdd(dst, a0);
            unsafeAtomicAdd(dst + 1, a1);
        }
    }
}

// ======================= tier-3 fallback =======================
__global__ __launch_bounds__(256) void edge_kernel(
    const int* __restrict__ z, const int* __restrict__ ei,
    const float* __restrict__ ew, const float* __restrict__ ea,
    const float* __restrict__ emb, const float* __restrict__ dpw,
    const float* __restrict__ dpb, float* __restrict__ agg, int E)
{
    int e = blockIdx.x * 256 + threadIdx.x;
    if (e >= E) return;
    float r = ew[e];
    if (!(r < CUTOFF_F)) return;
    float C = 0.5f * (cosf(r * PI_OVER_CUTOFF) + 1.0f);
    int src = ei[e];
    int dst = ei[E + e];
    int zt  = z[dst];
    float av[NRBF];
#pragma unroll
    for (int k = 0; k < NRBF; ++k) av[k] = ea[(size_t)e * NRBF + k];
    const float* er = emb + (size_t)zt * HIDDEN;
    float*       ar = agg + (size_t)src * HIDDEN;
#pragma unroll 2
    for (int h = 0; h < HIDDEN; ++h) {
        const float* wrow = dpw + h * NRBF;
        float s0 = 0.f, s1 = 0.f;
#pragma unroll
        for (int k = 0; k < NRBF; k += 2) {
            s0 = fmaf(av[k],     wrow[k],     s0);
            s1 = fmaf(av[k + 1], wrow[k + 1], s1);
        }
        float w2 = (dpb[h] + s0 + s1) * C;
        unsafeAtomicAdd(&ar[h], w2 * er[h]);
    }
}

// ======================= Combine: bf16 MFMA GEMM =======================
__global__ __launch_bounds__(256) void combine_mfma(
    const float* __restrict__ nf, const float* __restrict__ cw,
    const float* __restrict__ cbias, float* out, int N)
{
    __shared__ unsigned int As_u[64 * 20];
    __shared__ unsigned int Bs_u[128 * 20];
    int tid  = threadIdx.x;
    int w    = tid >> 6;
    int lane = tid & 63;
    int c    = lane & 15;
    int g    = lane >> 4;
    int row0 = blockIdx.x * 64;

    f32x4_t acc[8];
#pragma unroll
    for (int q = 0; q < 8; ++q) acc[q] = (f32x4_t){0.f, 0.f, 0.f, 0.f};

    for (int ks = 0; ks < 8; ++ks) {
        const float* src = (ks < 4) ? nf : out;
        int kb = (ks & 3) * 32;
        {
            int r = tid >> 2, kq = tid & 3;
            int row = row0 + r;
            float4 v0 = make_float4(0.f, 0.f, 0.f, 0.f), v1 = v0;
            if (row < N) {
                const float4* p = (const float4*)(src + (size_t)row * HIDDEN + kb + kq * 8);
                v0 = p[0]; v1 = p[1];
            }
            *(uint4*)&As_u[r * 20 + kq * 4] =
                make_uint4(pk_bf16(v0.x, v0.y), pk_bf16(v0.z, v0.w),
                           pk_bf16(v1.x, v1.y), pk_bf16(v1.z, v1.w));
        }
        {
            int j = tid >> 1, hf = tid & 1;
            const float4* p = (const float4*)(cw + (size_t)j * 256 + ks * 32 + hf * 16);
            float4 b0 = p[0], b1 = p[1], b2 = p[2], b3 = p[3];
            *(uint4*)&Bs_u[j * 20 + hf * 8] =
                make_uint4(pk_bf16(b0.x, b0.y), pk_bf16(b0.z, b0.w),
                           pk_bf16(b1.x, b1.y), pk_bf16(b1.z, b1.w));
            *(uint4*)&Bs_u[j * 20 + hf * 8 + 4] =
                make_uint4(pk_bf16(b2.x, b2.y), pk_bf16(b2.z, b2.w),
                           pk_bf16(b3.x, b3.y), pk_bf16(b3.z, b3.w));
        }
        __syncthreads();
        uint4 au = *(const uint4*)&As_u[(w * 16 + c) * 20 + g * 4];
        short8_t af = __builtin_bit_cast(short8_t, au);
#pragma unroll
        for (int cbk = 0; cbk < 8; ++cbk) {
            uint4 bu = *(const uint4*)&Bs_u[(cbk * 16 + c) * 20 + g * 4];
            short8_t bf = __builtin_bit_cast(short8_t, bu);
            acc[cbk] = __builtin_amdgcn_mfma_f32_16x16x32_bf16(af, bf, acc[cbk], 0, 0, 0);
        }
        __syncthreads();
    }
#pragma unroll
    for (int cbk = 0; cbk < 8; ++cbk) {
        float bias = cbias[cbk * 16 + c];
#pragma unroll
        for (int r = 0; r < 4; ++r) {
            int row = row0 + w * 16 + g * 4 + r;
            if (row < N) out[(size_t)row * HIDDEN + cbk * 16 + c] = acc[cbk][r] + bias;
        }
    }
}

// ======================= launch =======================

extern "C" void kernel_launch(void* const* d_in, const int* in_sizes, int n_in,
                              void* d_out, int out_size, void* d_ws, size_t ws_size,
                              hipStream_t stream)
{
    const int*   z   = (const int*)  d_in[0];
    const float* nf  = (const float*)d_in[1];
    const int*   ei  = (const int*)  d_in[2];
    const float* ew  = (const float*)d_in[3];
    const float* ea  = (const float*)d_in[4];
    const float* emb = (const float*)d_in[5];
    const float* dpw = (const float*)d_in[6];
    const float* dpb = (const float*)d_in[7];
    const float* cw  = (const float*)d_in[8];
    const float* cb  = (const float*)d_in[9];
    float* out = (float*)d_out;

    int N = in_sizes[0];
    int E = in_sizes[3];
    int NT = in_sizes[5] / HIDDEN;   // emb rows (95)

    size_t hdr  = ((size_t)2 * N + 1 + 1024 + 3) & ~(size_t)3;   // u32s
    size_t Epad = (size_t)E + 512;
    size_t need1 = (hdr + 3 * Epad + (size_t)NT * 64 + 16) * 4;
    size_t need2 = (hdr + (size_t)3 * E) * 4;

    (void)hipMemsetAsync(out, 0, (size_t)N * HIDDEN * sizeof(float), stream);

    int nb1 = (N + 1023) / 1024;

    if (ws_size >= need1) {
        int* rowptr = (int*)d_ws;
        int* woff   = rowptr + (N + 1);
        int* bsum   = woff + N;
        int* desc   = (int*)d_ws + hdr;
        int* eidA   = desc + Epad;
        float* CAa  = (float*)(eidA + Epad);
        unsigned int* embp = (unsigned int*)(CAa + Epad);

        (void)hipMemsetAsync(woff, 0, (size_t)N * 4, stream);
        hist_kernel<<<(E + 255) / 256, 256, 0, stream>>>(ei, ew, woff, E);
        scan1_kernel<<<nb1, 256, 0, stream>>>(woff, rowptr, bsum, N);
        scan2_kernel<<<1, 256, 0, stream>>>(bsum, rowptr, nb1, N);
        scan3_kernel<<<nb1, 256, 0, stream>>>(rowptr, woff, bsum, N);
        pack_emb<<<(NT * 64 + 255) / 256, 256, 0, stream>>>(emb, embp, NT);
        scatter_slim<<<(E + 255) / 256, 256, 0, stream>>>(z, ei, ew, woff,
                                                          desc, eidA, CAa, E);
        pad_kernel<<<2, 256, 0, stream>>>(rowptr, N, desc, eidA, CAa);
        int nblk = (E + EPB - 1) / EPB;
        gather_mfma<<<nblk, 256, 0, stream>>>(rowptr, desc, eidA, CAa, ea,
                                              embp, dpw, dpb, out, N);
    } else if (ws_size >= need2) {
        int* rowptr = (int*)d_ws;
        int* woff   = rowptr + (N + 1);
        int* bsum   = woff + N;
        int* desc   = (int*)d_ws + hdr;
        float* cCA  = (float*)(desc + E);
        int* eidA   = (int*)(cCA + E);

        (void)hipMemsetAsync(woff, 0, (size_t)N * 4, stream);
        hist_kernel<<<(E + 255) / 256, 256, 0, stream>>>(ei, ew, woff, E);
        scan1_kernel<<<nb1, 256, 0, stream>>>(woff, rowptr, bsum, N);
        scan2_kernel<<<1, 256, 0, stream>>>(bsum, rowptr, nb1, N);
        scan3_kernel<<<nb1, 256, 0, stream>>>(rowptr, woff, bsum, N);
        scatter_simple_fallback:
        {
            // reuse slim scatter layout for tier-2
        }
        scatter_slim<<<(E + 255) / 256, 256, 0, stream>>>(z, ei, ew, woff,
                                                          desc, eidA, (float*)cCA, E);
        const int blocks = 2048;
        gather_stream<<<blocks, 256, 0, stream>>>(rowptr, desc, cCA, eidA,
                                                  ea, emb, dpw, dpb, out, N,
                                                  blocks * 4);
    } else {
        edge_kernel<<<(E + 255) / 256, 256, 0, stream>>>(z, ei, ew, ea, emb,
                                                         dpw, dpb, out, E);
    }

    combine_mfma<<<(N + 63) / 64, 256, 0, stream>>>(nf, cw, cb, out, N);
}